// Round 3
// baseline (334.059 us; speedup 1.0000x reference)
//
#include <hip/hip_runtime.h>
#include <hip/hip_bf16.h>
#include <math.h>

typedef unsigned short u16;

// Wave-local LDS drain: each phase-2 LDS region is touched by exactly ONE wave.
#define WAVE_SYNC() asm volatile("s_waitcnt lgkmcnt(0)" ::: "memory")

// ---------- dtype helpers ----------
__device__ __forceinline__ float bf2f(u16 u) {
  union { unsigned int i; float f; } c;
  c.i = ((unsigned int)u) << 16;
  return c.f;
}
__device__ __forceinline__ float bflo(unsigned int u) {
  union { unsigned int i; float f; } c; c.i = u << 16; return c.f;
}
__device__ __forceinline__ float bfhi(unsigned int u) {
  union { unsigned int i; float f; } c; c.i = u & 0xffff0000u; return c.f;
}
__device__ __forceinline__ u16 f2bf(float f) {
  union { float f; unsigned int i; } c;
  c.f = f;
  unsigned int x = c.i;
  unsigned int r = (x + 0x7fffu + ((x >> 16) & 1u)) >> 16; // RNE
  return (u16)r;
}

// Destination-bin bounds for proj of supports (-10+0.4t)*wv, t=0..50, wv>=0.
__device__ __forceinline__ void proj_bounds(float wv, int& ML, int& MH) {
  float smin = (-10.0f + 0.4f * 0.0f)  * wv;
  float smax = (-10.0f + 0.4f * 50.0f) * wv;
  float bmin = (fminf(fmaxf(smin, -10.0f), 10.0f) + 10.0f) / 0.4f;
  float bmax = (fminf(fmaxf(smax, -10.0f), 10.0f) + 10.0f) / 0.4f;
  ML = (int)floorf(bmin);
  MH = (int)ceilf(bmax);
}

// ---------- atomic-free projection via segmented scan (elu + final) ---------
template<typename SUPP>
__device__ __forceinline__ void proj_scan(float* __restrict__ g1,
                                          float* __restrict__ g2,
                                          int span, int lane, SUPP supp)
{
  if (lane < 52) g1[lane] = 0.f;
  if (lane < 53) g2[lane] = 0.f;
  float cml = 0.f, cmu = 0.f;
  int ck = -1;
  for (int base = 0; base < span; base += 64) {
    int t = base + lane;
    bool act = (t < span);
    int tc = act ? t : (span - 1);
    float sup, p;
    supp(tc, act, sup, p);
    float c  = fminf(fmaxf(sup, -10.0f), 10.0f);
    float b  = (c + 10.0f) / 0.4f;
    float l  = floorf(b);
    float u  = ceilf(b);
    float eq = (u == l) ? 1.0f : 0.0f;
    float ml = p * (u - b + eq);
    float mu = p * (b - l);
    int   li = (int)l;
    bool last = (base + 64 >= span);
    if (lane == 0 && ck >= 0) {
      if (ck == li) { ml += cml; mu += cmu; }
      else          { g1[ck] = cml; g2[ck + 1] = cmu; }
    }
#pragma unroll
    for (int d = 1; d < 64; d <<= 1) {
      int   lo = __shfl_up(li, d);
      float a1 = __shfl_up(ml, d);
      float a2 = __shfl_up(mu, d);
      bool same = (lane >= d) && (lo == li);
      ml += same ? a1 : 0.f;
      mu += same ? a2 : 0.f;
    }
    int ln = __shfl_down(li, 1);
    bool runend = (lane == 63) ? last : (ln != li);
    if (runend) { g1[li] = ml; g2[li + 1] = mu; }
    if (!last) {
      cml = __shfl(ml, 63);
      cmu = __shfl(mu, 63);
      ck  = __shfl(li, 63);
    }
  }
}

// ---------- runtime-width convolution (wide agents only) --------------------
__device__ __forceinline__ void conv_pad2(const float* __restrict__ q,
                                          float* __restrict__ qn,
                                          const float* __restrict__ kvs,
                                          int ML, int W, int T,
                                          int LQ, int HQ, int tid, int nthr)
{
  const int Lout = LQ + ML, Hout = HQ + ML + T;
  for (int J = Lout + tid; J <= Hout; J += nthr) {
    const float* qp = q + (J - ML);
    float acc = 0.f;
    for (int c = 0; c < W; c += 4) {
      float4 k4 = *(const float4*)(kvs + c);   // uniform address -> broadcast
      acc = fmaf(k4.x, qp[-c],     acc);
      acc = fmaf(k4.y, qp[-c - 1], acc);
      acc = fmaf(k4.z, qp[-c - 2], acc);
      acc = fmaf(k4.w, qp[-c - 3], acc);
    }
    qn[J] = acc;
  }
}

// ---------- fixed 16-tap fully-unrolled convolution (narrow agents) ---------
__device__ __forceinline__ void conv16(const float* __restrict__ q,
                                       float* __restrict__ qn,
                                       const float* __restrict__ kvs,
                                       int ML, int T,
                                       int LQ, int HQ, int tid, int nthr)
{
  const int Lout = LQ + ML, Hout = HQ + ML + T;
  for (int J = Lout + tid; J <= Hout; J += nthr) {
    const float* qp = q + (J - ML);
    float a0 = 0.f, a1 = 0.f;
#pragma unroll
    for (int c = 0; c < 16; c += 4) {
      float4 k4 = *(const float4*)(kvs + c);   // uniform -> broadcast
      a0 = fmaf(k4.x, qp[-c],     a0);
      a1 = fmaf(k4.y, qp[-c - 1], a1);
      a0 = fmaf(k4.z, qp[-c - 2], a0);
      a1 = fmaf(k4.w, qp[-c - 3], a1);
    }
    qn[J] = a0 + a1;
  }
}

// ---------- all-atom gather with clamp (wide agents / wide wf) --------------
template<int TA, int TB>
__device__ __forceinline__ float gather_part(const float* __restrict__ pb,
                                             float wv, float j)
{
  float a0 = 0.f, a1 = 0.f, a2 = 0.f, a3 = 0.f;
  const float4* pb4 = (const float4*)pb;
  const float base = 25.0f - j;
#pragma unroll
  for (int t4 = TA; t4 < TB; ++t4) {
    float4 p4 = pb4[t4];
#define G1(PX, TT, AC) { \
    float sup = ((float)(TT) * 0.4f - 10.0f) * wv; \
    float c   = fminf(fmaxf(sup, -10.0f), 10.0f); \
    float d   = fmaf(c, 2.5f, base); \
    AC = fmaf(PX, fmaxf(0.f, 1.0f - fabsf(d)), AC); }
    G1(p4.x, 4 * t4 + 0, a0)
    G1(p4.y, 4 * t4 + 1, a1)
    G1(p4.z, 4 * t4 + 2, a2)
    G1(p4.w, 4 * t4 + 3, a3)
#undef G1
  }
  return (a0 + a1) + (a2 + a3);
}

// ---------- typed loads / dot rows ----------
template<int BF>
__device__ __forceinline__ float ldt(const void* p, int i) {
  if (BF) return bf2f(((const u16*)p)[i]);
  return ((const float*)p)[i];
}

template<int BF>
__device__ __forceinline__ float dot128_t(const void* w, int row, const float* s) {
  float acc = 0.f;
  if (BF) {
    const uint4* p = (const uint4*)((const u16*)w + row * 128);
#pragma unroll
    for (int i = 0; i < 16; ++i) {
      uint4 v = p[i];
      int b = i * 8;
      acc = fmaf(bflo(v.x), s[b + 0], acc); acc = fmaf(bfhi(v.x), s[b + 1], acc);
      acc = fmaf(bflo(v.y), s[b + 2], acc); acc = fmaf(bfhi(v.y), s[b + 3], acc);
      acc = fmaf(bflo(v.z), s[b + 4], acc); acc = fmaf(bfhi(v.z), s[b + 5], acc);
      acc = fmaf(bflo(v.w), s[b + 6], acc); acc = fmaf(bfhi(v.w), s[b + 7], acc);
    }
  } else {
    const float4* p = (const float4*)((const float*)w + row * 128);
#pragma unroll
    for (int i = 0; i < 32; ++i) {
      float4 v = p[i];
      int b = i * 4;
      acc = fmaf(v.x, s[b + 0], acc); acc = fmaf(v.y, s[b + 1], acc);
      acc = fmaf(v.z, s[b + 2], acc); acc = fmaf(v.w, s[b + 3], acc);
    }
  }
  return acc;
}

template<int BF>
__device__ __forceinline__ float dot64_t(const void* w, int row, const float* h) {
  float acc = 0.f;
  if (BF) {
    const uint4* p = (const uint4*)((const u16*)w + row * 64);
#pragma unroll
    for (int i = 0; i < 8; ++i) {
      uint4 v = p[i];
      int b = i * 8;
      acc = fmaf(bflo(v.x), h[b + 0], acc); acc = fmaf(bfhi(v.x), h[b + 1], acc);
      acc = fmaf(bflo(v.y), h[b + 2], acc); acc = fmaf(bfhi(v.y), h[b + 3], acc);
      acc = fmaf(bflo(v.z), h[b + 4], acc); acc = fmaf(bfhi(v.z), h[b + 5], acc);
      acc = fmaf(bflo(v.w), h[b + 6], acc); acc = fmaf(bfhi(v.w), h[b + 7], acc);
    }
  } else {
    const float4* p = (const float4*)((const float*)w + row * 64);
#pragma unroll
    for (int i = 0; i < 16; ++i) {
      float4 v = p[i];
      int b = i * 4;
      acc = fmaf(v.x, h[b + 0], acc); acc = fmaf(v.y, h[b + 1], acc);
      acc = fmaf(v.z, h[b + 2], acc); acc = fmaf(v.w, h[b + 3], acc);
    }
  }
  return acc;
}

// ============================================================================
// Fused kernel: one block per n (1024 blocks x 512 threads).
//  Phase 1: hypernet MLPs, 320 parallel dot-rows (once per n, not per wave).
//  Phase 2: 32 embed tasks = 8 waves x 4 sequential tasks, ZERO block barriers
//           inside (wave-local LDS regions + WAVE_SYNC only). p_lds staged once.
//  Phase 3: k_final tree conv in-block; xw never leaves LDS.
// LDS ~57 KB -> 2 blocks/CU (16 waves/CU) vs ~11-14 effective before, and the
// two inter-kernel drains + k_mlp's 1-wave/SIMD latency + 13.4 MB xw HBM
// round-trip all disappear.
// ============================================================================
template<int BF>
__device__ void fused_body(
    const void* __restrict__ aq, const void* __restrict__ states,
    const void* __restrict__ hw1_w1, const void* __restrict__ hw1_b1,
    const void* __restrict__ hw1_w2, const void* __restrict__ hw1_b2,
    const void* __restrict__ hb1_w,  const void* __restrict__ hb1_b,
    const void* __restrict__ hwf_w1, const void* __restrict__ hwf_b1,
    const void* __restrict__ hwf_w2, const void* __restrict__ hwf_b2,
    const void* __restrict__ v_w1,   const void* __restrict__ v_b1,
    const void* __restrict__ v_w2,   const void* __restrict__ v_b2,
    void* __restrict__ out,
    float* SH, float* xw_lds, float* p_lds, float* s_st,
    float* h1, float* hf, float* vh,
    float* w1s, float* b1s, float* wfs, float* vs,
    int* meta_s, int* meta_l, int* meta_ml, int* meta_g, int* meta_mltot,
    int n, int tid)
{
  const int lane = tid & 63;
  const int w    = tid >> 6;

  // ---------------- phase 1: MLPs + staging ----------------
  if (tid < 128) s_st[tid] = ldt<BF>(states, n * 128 + tid);
  if (tid >= 192) {
    for (int u = tid - 192; u < 416; u += 320) {   // p_lds[8][52], pad col 51 = 0
      int a = u / 52, c2 = u - a * 52;
      p_lds[u] = (c2 < 51) ? ldt<BF>(aq, n * 408 + a * 51 + c2) : 0.f;
    }
  }
  __syncthreads();
  if (tid < 64)       h1[tid]        = fmaxf(dot128_t<BF>(hw1_w1, tid, s_st) + ldt<BF>(hw1_b1, tid), 0.f);
  else if (tid < 128) hf[tid - 64]   = fmaxf(dot128_t<BF>(hwf_w1, tid - 64, s_st) + ldt<BF>(hwf_b1, tid - 64), 0.f);
  else if (tid < 160) vh[tid - 128]  = fmaxf(dot128_t<BF>(v_w1, tid - 128, s_st) + ldt<BF>(v_b1, tid - 128), 0.f);
  else if (tid < 192) b1s[tid - 160] = dot128_t<BF>(hb1_w, tid - 160, s_st) + ldt<BF>(hb1_b, tid - 160);
  __syncthreads();
  if (tid < 256)      w1s[tid]       = fabsf(dot64_t<BF>(hw1_w2, tid, h1) + ldt<BF>(hw1_b2, tid));
  else if (tid < 288) wfs[tid - 256] = fabsf(dot64_t<BF>(hwf_w2, tid - 256, hf) + ldt<BF>(hwf_b2, tid - 256));
  else if (tid < 320) {
    int l2 = tid - 288;                                  // wave 4, lanes 32..63
    float part = vh[l2] * ldt<BF>(v_w2, l2);
    part += __shfl_xor(part, 1);  part += __shfl_xor(part, 2);
    part += __shfl_xor(part, 4);  part += __shfl_xor(part, 8);
    part += __shfl_xor(part, 16);
    if (l2 == 0) vs[0] = part + ldt<BF>(v_b2, 0);
  }
  __syncthreads();

  // ---------------- phase 2: 8 waves x 4 embed tasks, no block barriers -----
  {
    float* WB  = SH + w * 1408;   // per-wave scratch (5.5 KB)
    float* Ab  = WB;              // 520
    float* Bb  = WB + 520;        // 520
    float* kv  = WB + 1040;       // 8 x 16
    float* kvo = WB + 1168;       // 56
    float* x2  = WB + 1224;       // 52 (+pad)
    float* gA  = WB + 1280;       // 53
    float* gB  = WB + 1333;       // 54
#pragma unroll 1
    for (int i = 0; i < 4; ++i) {
      const int e   = w + 8 * i;
      const float b1v = b1s[e];
      const float wfv = wfs[e];

      // narrow gathers: 2 rounds x (4 agents x 16 bins); T<=15 => wv<=~0.3,
      // |sup|<=3 so no clamp needed.
#pragma unroll
      for (int r = 0; r < 2; ++r) {
        int a  = 4 * r + (lane >> 4);
        int jj = lane & 15;
        float wv = w1s[e * 8 + a];
        int ML, MH; proj_bounds(wv, ML, MH);
        int T  = MH - ML;
        float K = (25.0f - (float)(ML + jj)) - 25.0f * wv;
        float a0 = 0.f, a1 = 0.f, a2 = 0.f, a3 = 0.f;
        const float4* pb4 = (const float4*)(p_lds + a * 52);
#pragma unroll
        for (int t4 = 0; t4 < 13; ++t4) {
          float4 p4 = pb4[t4];
          float d0 = fmaf((float)(4 * t4 + 0), wv, K);
          float d1 = fmaf((float)(4 * t4 + 1), wv, K);
          float d2 = fmaf((float)(4 * t4 + 2), wv, K);
          float d3 = fmaf((float)(4 * t4 + 3), wv, K);
          a0 = fmaf(p4.x, fmaxf(0.f, 1.0f - fabsf(d0)), a0);
          a1 = fmaf(p4.y, fmaxf(0.f, 1.0f - fabsf(d1)), a1);
          a2 = fmaf(p4.z, fmaxf(0.f, 1.0f - fabsf(d2)), a2);
          a3 = fmaf(p4.w, fmaxf(0.f, 1.0f - fabsf(d3)), a3);
        }
        if (T <= 15)
          kv[a * 16 + jj] = (jj <= T) ? ((a0 + a1) + (a2 + a3)) : 0.f;
      }
      WAVE_SYNC();

      // seed: agent 0
      float* q = Ab; float* qn = Bb;
      int LQ, HQ;
      {
        float wv0 = w1s[e * 8];
        int ML0, MH0; proj_bounds(wv0, ML0, MH0);
        int T0 = MH0 - ML0;
        if (T0 <= 15) {
          if (lane <= T0) Ab[64 + ML0 + lane] = kv[lane];
        } else {
          float acc = gather_part<0, 13>(p_lds, wv0, (float)(ML0 + lane));
          if (lane <= T0) Ab[64 + ML0 + lane] = acc;
        }
        WAVE_SYNC();
        LQ = 64 + ML0; HQ = 64 + MH0;
      }

      // conv chain over agents 1..7
      for (int a = 1; a < 8; ++a) {
        float wv = w1s[e * 8 + a];
        int ML, MH; proj_bounds(wv, ML, MH);
        int T = MH - ML;
        const float* kvs; int W;
        if (T <= 15) {                    // wave-uniform branch
          kvs = kv + a * 16; W = 16;
        } else {                          // rare wide agent
          float acc = gather_part<0, 13>(p_lds + a * 52, wv, (float)(ML + lane));
          W = (T + 4) & ~3;               // <= 52
          if (lane < W) kvo[lane] = (lane <= T) ? acc : 0.f;
          kvs = kvo;
        }
        if (lane < W - 1) q[LQ - 1 - lane] = 0.f;
        if (lane < T)     q[HQ + 1 + lane] = 0.f;
        WAVE_SYNC();
        if (T <= 15) conv16(q, qn, kvs, ML, T, LQ, HQ, lane, 64);
        else         conv_pad2(q, qn, kvs, ML, W, T, LQ, HQ, lane, 64);
        WAVE_SYNC();
        LQ += ML; HQ += MH;
        float* t_ = q; q = qn; qn = t_;
      }

      // elu projection (chunked scan over claimed span)
      {
        int span = HQ - LQ + 1, LQl = LQ;
        const float* qf = q;
        proj_scan(gA, gB, span, lane, [&](int t, bool act, float& sup, float& p) {
          int tg = (LQl - 64) + t;        // grid index in [0,400]
          float raw = (-80.0f + 0.4f * (float)tg) + b1v;
          sup = (raw > 0.f) ? raw : expm1f(raw);
          p = act ? qf[LQl + t] : 0.f;
        });
      }
      WAVE_SYNC();
      float x2v = (lane < 51) ? (gA[lane] + gB[lane]) : 0.f;
      if (lane < 52) x2[lane] = (lane < 51) ? x2v : 0.f;
      WAVE_SYNC();

      // wf projection -> xw_lds row e
      {
        int MLf, MHf; proj_bounds(wfv, MLf, MHf);
        int Tf = MHf - MLf;
        if (Tf <= 15) {
          // strided split: lane = q4*16+jj gathers atoms t = q4+4k (no clamp,
          // wv<=~0.3); combine the 4 quarters with 2 shfl_xor.
          int q4 = lane >> 4, jj = lane & 15;
          float K = (25.0f - (float)(MLf + jj)) - 25.0f * wfv;
          float acc = 0.f;
#pragma unroll
          for (int k = 0; k < 13; ++k) {
            int t = q4 + 4 * k;
            float d = fmaf((float)t, wfv, K);
            acc = fmaf(x2[t], fmaxf(0.f, 1.0f - fabsf(d)), acc);
          }
          acc += __shfl_xor(acc, 16);
          acc += __shfl_xor(acc, 32);
          if (lane <= Tf)                 // Tf<=15 -> lanes 0..15, jj==lane
            xw_lds[e * 52 + MLf + lane] = acc;
        } else {
          float acc = gather_part<0, 13>(x2, wfv, (float)(MLf + lane));
          if (lane <= Tf)
            xw_lds[e * 52 + MLf + lane] = acc;
        }
      }
      WAVE_SYNC();
    }
  }
  __syncthreads();                        // all xw rows ready; wave bufs dead

  // ---------------- phase 3: tree convolution (aliases SH) ----------------
  float* bufA = SH;                       // 4608
  float* bufB = SH + 4608;                // 4608
  float* gA3  = SH + 9216;                // 53  (outside bufA/bufB)
  float* gB3  = SH + 9269;                // 54

  float wfreg = (lane < 32) ? wfs[lane] : 0.f;
  float vv    = vs[0];

  for (int i2 = tid; i2 < 4608; i2 += 512) { bufA[i2] = 0.f; bufB[i2] = 0.f; }

  if (tid < 64) {
    int ml, mh;
    proj_bounds(wfreg, ml, mh);
    if (lane < 32) meta_ml[lane] = ml;
    int msum = ml;
#pragma unroll
    for (int d = 1; d < 32; d <<= 1) msum += __shfl_xor(msum, d);
    if (lane == 0) *meta_mltot = msum;

    int curlen = mh - ml + 1;
    int base = 0, Ncur = 32;
#pragma unroll
    for (int c = 0; c <= 5; ++c) {
      int lm = (lane < Ncur) ? curlen : 0;
#pragma unroll
      for (int d = 1; d < 32; d <<= 1) {
        int o = __shfl_xor(lm, d);
        lm = (o > lm) ? o : lm;
      }
      int G = (lm + 11) & ~3;
      int sp = ((curlen + 3) & ~3) + G;
      int inc = (lane < Ncur) ? sp : 0;
      int v0 = inc;
#pragma unroll
      for (int d = 1; d < 32; d <<= 1) {
        int u = __shfl_up(inc, d);
        if (lane >= d && lane < 32) inc += u;
      }
      if (lane < Ncur) {
        meta_s[base + lane] = 832 + (inc - v0);
        meta_l[base + lane] = curlen;
      }
      if (lane == 0) meta_g[c] = G;
      if (c < 5) {
        int l0 = __shfl(curlen, 2 * lane);
        int l1 = __shfl(curlen, 2 * lane + 1);
        curlen = l0 + l1 - 1;
        base += Ncur;
        Ncur >>= 1;
      }
    }
  }
  __syncthreads();

  {
    int g = tid >> 4, i3 = tid & 15;      // 16 threads per embed row
    int s2 = meta_s[g], l2 = meta_l[g], ml = meta_ml[g];
    const float* row = xw_lds + g * 52 + ml;
    for (int i0 = i3; i0 < l2; i0 += 16) bufA[s2 + i0] = row[i0];
  }
  __syncthreads();

#pragma unroll
  for (int c = 1; c <= 5; ++c) {
    const float* bin = (c & 1) ? bufA : bufB;
    float*       bout = (c & 1) ? bufB : bufA;
    const int Nout = 32 >> c;
    const int lg = 4 + c;                 // 512-thread split: gs*Nout == 512
    const int gs = 1 << lg;
    const int k  = tid >> lg;
    const int st = tid & (gs - 1);
    const int bc = 64 - (64 >> c);
    const int bp = 64 - (64 >> (c - 1));
    const int i0 = bp + 2 * k;
    const int sA = meta_s[i0];
    const int sB = meta_s[i0 + 1];
    const int lB = meta_l[i0 + 1];
    const int sO = meta_s[bc + k];
    const int lO = meta_l[bc + k];
    const int W  = (lB + 3) & ~3;

    for (int j = st * 2; j < lO; j += gs * 2) {
      const float* Ap = bin + sA + j + 1;
      float a0 = 0.f, a1 = 0.f;
      for (int m = 0; m < W; m += 4) {
        float4 k4 = *(const float4*)(bin + sB + m);
        float v0 = Ap[-m], v1 = Ap[-m - 1], v2 = Ap[-m - 2];
        float v3 = Ap[-m - 3], v4 = Ap[-m - 4];
        a0 = fmaf(k4.x, v1, fmaf(k4.y, v2, fmaf(k4.z, v3, fmaf(k4.w, v4, a0))));
        a1 = fmaf(k4.x, v0, fmaf(k4.y, v1, fmaf(k4.z, v2, fmaf(k4.w, v3, a1))));
      }
      bout[sO + j] = a0;
      if (j + 1 < lO) bout[sO + j + 1] = a1;
    }

    if (c >= 2 && c <= 4) {
      int G = meta_g[c];
      for (int p = tid; p < G; p += 512) bout[832 - G + p] = 0.f;
      for (int k2 = 0; k2 < Nout; ++k2) {
        int ss = meta_s[bc + k2] + meta_l[bc + k2];
        int ee = (k2 + 1 < Nout) ? meta_s[bc + k2 + 1]
                                 : ss + G + 3;
        for (int p = ss + tid; p < ee; p += 512) bout[p] = 0.f;
      }
    }
    __syncthreads();
  }

  if (tid < 64) {
    int s5 = meta_s[62], l5 = meta_l[62], mlt = *meta_mltot;
    const float* qf = bufB + s5;
    proj_scan(gA3, gB3, l5, lane, [&](int t, bool act, float& sup, float& p) {
      int tg = mlt + t;
      sup = (-320.0f + 0.4f * (float)tg) + vv;
      p = act ? qf[t] : 0.f;
    });
    WAVE_SYNC();
    if (lane < 51) {
      float o = gA3[lane] + gB3[lane];
      if (BF) ((u16*)out)[n * 51 + lane] = f2bf(o);
      else    ((float*)out)[n * 51 + lane] = o;
    }
  }
}

__global__ __launch_bounds__(512) void k_fused(
    const void* __restrict__ aq, const void* __restrict__ states,
    const void* __restrict__ hw1_w1, const void* __restrict__ hw1_b1,
    const void* __restrict__ hw1_w2, const void* __restrict__ hw1_b2,
    const void* __restrict__ hb1_w,  const void* __restrict__ hb1_b,
    const void* __restrict__ hwf_w1, const void* __restrict__ hwf_b1,
    const void* __restrict__ hwf_w2, const void* __restrict__ hwf_b2,
    const void* __restrict__ v_w1,   const void* __restrict__ v_b1,
    const void* __restrict__ v_w2,   const void* __restrict__ v_b2,
    void* __restrict__ out)
{
  __shared__ __align__(16) float SH[11264];       // 8 x 1408 wave scratch; aliased by tree
  __shared__ __align__(16) float xw_lds[32 * 52];
  __shared__ __align__(16) float p_lds[8 * 52];
  __shared__ __align__(16) float s_st[128];
  __shared__ float h1[64], hf[64], vh[32];
  __shared__ __align__(16) float w1s[256];
  __shared__ float b1s[32], wfs[32], vs[1];
  __shared__ int meta_s[63], meta_l[63], meta_ml[32], meta_g[6], meta_mltot;
  __shared__ int sh_flag;

  const int tid = threadIdx.x;
  const int n   = blockIdx.x;

  // inline dtype detect (wave 0): first 128 u16 words of states (~N(0,1))
  if (tid < 64) {
    const u16* sr = (const u16*)states;
    unsigned int e0 = (sr[tid] >> 7) & 0xFF;
    unsigned int e1 = (sr[tid + 64] >> 7) & 0xFF;
    unsigned long long bl0 = __ballot(e0 >= 97 && e0 <= 141);
    unsigned long long bl1 = __ballot(e1 >= 97 && e1 <= 141);
    int bfv = (__popcll(bl0) + __popcll(bl1) >= 104) ? 1 : 0;
    if (tid == 0) sh_flag = bfv;
  }
  __syncthreads();
  const int bf = sh_flag;                 // block-uniform

  if (bf)
    fused_body<1>(aq, states, hw1_w1, hw1_b1, hw1_w2, hw1_b2, hb1_w, hb1_b,
                  hwf_w1, hwf_b1, hwf_w2, hwf_b2, v_w1, v_b1, v_w2, v_b2, out,
                  SH, xw_lds, p_lds, s_st, h1, hf, vh, w1s, b1s, wfs, vs,
                  meta_s, meta_l, meta_ml, meta_g, &meta_mltot, n, tid);
  else
    fused_body<0>(aq, states, hw1_w1, hw1_b1, hw1_w2, hw1_b2, hb1_w, hb1_b,
                  hwf_w1, hwf_b1, hwf_w2, hwf_b2, v_w1, v_b1, v_w2, v_b2, out,
                  SH, xw_lds, p_lds, s_st, h1, hf, vh, w1s, b1s, wfs, vs,
                  meta_s, meta_l, meta_ml, meta_g, &meta_mltot, n, tid);
}

// =========================== launcher ===========================
extern "C" void kernel_launch(void* const* d_in, const int* in_sizes, int n_in,
                              void* d_out, int out_size, void* d_ws, size_t ws_size,
                              hipStream_t stream)
{
  (void)d_ws; (void)ws_size; (void)in_sizes; (void)n_in; (void)out_size;
  k_fused<<<1024, 512, 0, stream>>>(
      d_in[0], d_in[1],
      d_in[2], d_in[3], d_in[4], d_in[5], d_in[6], d_in[7],
      d_in[8], d_in[9], d_in[10], d_in[11], d_in[12], d_in[13],
      d_in[14], d_in[15],
      d_out);
}

// Round 4
// 254.814 us; speedup vs baseline: 1.3110x; 1.3110x over previous
//
#include <hip/hip_runtime.h>
#include <hip/hip_bf16.h>
#include <math.h>

typedef unsigned short u16;

// Wave-local LDS drain (same-wave DS ops execute in order; this also fences
// the compiler).
#define WAVE_SYNC() asm volatile("s_waitcnt lgkmcnt(0)" ::: "memory")

// ---------- dtype helpers ----------
__device__ __forceinline__ float bf2f(u16 u) {
  union { unsigned int i; float f; } c;
  c.i = ((unsigned int)u) << 16;
  return c.f;
}
__device__ __forceinline__ float bflo(unsigned int u) {
  union { unsigned int i; float f; } c; c.i = u << 16; return c.f;
}
__device__ __forceinline__ float bfhi(unsigned int u) {
  union { unsigned int i; float f; } c; c.i = u & 0xffff0000u; return c.f;
}
__device__ __forceinline__ u16 f2bf(float f) {
  union { float f; unsigned int i; } c;
  c.f = f;
  unsigned int x = c.i;
  unsigned int r = (x + 0x7fffu + ((x >> 16) & 1u)) >> 16; // RNE
  return (u16)r;
}

// Destination-bin bounds for proj of supports (-10+0.4t)*wv, t=0..50, wv>=0.
__device__ __forceinline__ void proj_bounds(float wv, int& ML, int& MH) {
  float smin = (-10.0f + 0.4f * 0.0f)  * wv;
  float smax = (-10.0f + 0.4f * 50.0f) * wv;
  float bmin = (fminf(fmaxf(smin, -10.0f), 10.0f) + 10.0f) / 0.4f;
  float bmax = (fminf(fmaxf(smax, -10.0f), 10.0f) + 10.0f) / 0.4f;
  ML = (int)floorf(bmin);
  MH = (int)ceilf(bmax);
}

// ---------- runtime-width convolution (wide agents only) --------------------
__device__ __forceinline__ void conv_pad2(const float* __restrict__ q,
                                          float* __restrict__ qn,
                                          const float* __restrict__ kvs,
                                          int ML, int W, int T,
                                          int LQ, int HQ, int tid, int nthr)
{
  const int Lout = LQ + ML, Hout = HQ + ML + T;
  for (int J = Lout + tid; J <= Hout; J += nthr) {
    const float* qp = q + (J - ML);
    float acc = 0.f;
    for (int c = 0; c < W; c += 4) {
      float4 k4 = *(const float4*)(kvs + c);   // uniform address -> broadcast
      acc = fmaf(k4.x, qp[-c],     acc);
      acc = fmaf(k4.y, qp[-c - 1], acc);
      acc = fmaf(k4.z, qp[-c - 2], acc);
      acc = fmaf(k4.w, qp[-c - 3], acc);
    }
    qn[J] = acc;
  }
}

// ---------- fixed-tap fully-unrolled convolutions (narrow agents) -----------
__device__ __forceinline__ void conv16(const float* __restrict__ q,
                                       float* __restrict__ qn,
                                       const float* __restrict__ kvs,
                                       int ML, int T,
                                       int LQ, int HQ, int tid, int nthr)
{
  const int Lout = LQ + ML, Hout = HQ + ML + T;
  for (int J = Lout + tid; J <= Hout; J += nthr) {
    const float* qp = q + (J - ML);
    float a0 = 0.f, a1 = 0.f;
#pragma unroll
    for (int c = 0; c < 16; c += 4) {
      float4 k4 = *(const float4*)(kvs + c);   // uniform -> broadcast
      a0 = fmaf(k4.x, qp[-c],     a0);
      a1 = fmaf(k4.y, qp[-c - 1], a1);
      a0 = fmaf(k4.z, qp[-c - 2], a0);
      a1 = fmaf(k4.w, qp[-c - 3], a1);
    }
    qn[J] = a0 + a1;
  }
}

__device__ __forceinline__ void conv8(const float* __restrict__ q,
                                      float* __restrict__ qn,
                                      const float* __restrict__ kvs,
                                      int ML, int T,
                                      int LQ, int HQ, int tid, int nthr)
{
  const int Lout = LQ + ML, Hout = HQ + ML + T;
  for (int J = Lout + tid; J <= Hout; J += nthr) {
    const float* qp = q + (J - ML);
    float a0 = 0.f, a1 = 0.f;
#pragma unroll
    for (int c = 0; c < 8; c += 4) {
      float4 k4 = *(const float4*)(kvs + c);   // uniform -> broadcast
      a0 = fmaf(k4.x, qp[-c],     a0);
      a1 = fmaf(k4.y, qp[-c - 1], a1);
      a0 = fmaf(k4.z, qp[-c - 2], a0);
      a1 = fmaf(k4.w, qp[-c - 3], a1);
    }
    qn[J] = a0 + a1;
  }
}

// ---------- all-atom gather with clamp (wide agents / wide wf) --------------
template<int TA, int TB>
__device__ __forceinline__ float gather_part(const float* __restrict__ pb,
                                             float wv, float j)
{
  float a0 = 0.f, a1 = 0.f, a2 = 0.f, a3 = 0.f;
  const float4* pb4 = (const float4*)pb;
  const float base = 25.0f - j;
#pragma unroll
  for (int t4 = TA; t4 < TB; ++t4) {
    float4 p4 = pb4[t4];
#define G1(PX, TT, AC) { \
    float sup = ((float)(TT) * 0.4f - 10.0f) * wv; \
    float c   = fminf(fmaxf(sup, -10.0f), 10.0f); \
    float d   = fmaf(c, 2.5f, base); \
    AC = fmaf(PX, fmaxf(0.f, 1.0f - fabsf(d)), AC); }
    G1(p4.x, 4 * t4 + 0, a0)
    G1(p4.y, 4 * t4 + 1, a1)
    G1(p4.z, 4 * t4 + 2, a2)
    G1(p4.w, 4 * t4 + 3, a3)
#undef G1
  }
  return (a0 + a1) + (a2 + a3);
}

// ---------- typed loads / dot rows ----------
template<int BF>
__device__ __forceinline__ float ldt(const void* p, int i) {
  if (BF) return bf2f(((const u16*)p)[i]);
  return ((const float*)p)[i];
}

template<int BF>
__device__ __forceinline__ float dot128_t(const void* w, int row, const float* s) {
  float acc = 0.f;
  if (BF) {
    const uint4* p = (const uint4*)((const u16*)w + row * 128);
#pragma unroll
    for (int i = 0; i < 16; ++i) {
      uint4 v = p[i];
      int b = i * 8;
      acc = fmaf(bflo(v.x), s[b + 0], acc); acc = fmaf(bfhi(v.x), s[b + 1], acc);
      acc = fmaf(bflo(v.y), s[b + 2], acc); acc = fmaf(bfhi(v.y), s[b + 3], acc);
      acc = fmaf(bflo(v.z), s[b + 4], acc); acc = fmaf(bfhi(v.z), s[b + 5], acc);
      acc = fmaf(bflo(v.w), s[b + 6], acc); acc = fmaf(bfhi(v.w), s[b + 7], acc);
    }
  } else {
    const float4* p = (const float4*)((const float*)w + row * 128);
#pragma unroll
    for (int i = 0; i < 32; ++i) {
      float4 v = p[i];
      int b = i * 4;
      acc = fmaf(v.x, s[b + 0], acc); acc = fmaf(v.y, s[b + 1], acc);
      acc = fmaf(v.z, s[b + 2], acc); acc = fmaf(v.w, s[b + 3], acc);
    }
  }
  return acc;
}

template<int BF>
__device__ __forceinline__ float dot64_t(const void* w, int row, const float* h) {
  float acc = 0.f;
  if (BF) {
    const uint4* p = (const uint4*)((const u16*)w + row * 64);
#pragma unroll
    for (int i = 0; i < 8; ++i) {
      uint4 v = p[i];
      int b = i * 8;
      acc = fmaf(bflo(v.x), h[b + 0], acc); acc = fmaf(bfhi(v.x), h[b + 1], acc);
      acc = fmaf(bflo(v.y), h[b + 2], acc); acc = fmaf(bfhi(v.y), h[b + 3], acc);
      acc = fmaf(bflo(v.z), h[b + 4], acc); acc = fmaf(bfhi(v.z), h[b + 5], acc);
      acc = fmaf(bflo(v.w), h[b + 6], acc); acc = fmaf(bfhi(v.w), h[b + 7], acc);
    }
  } else {
    const float4* p = (const float4*)((const float*)w + row * 64);
#pragma unroll
    for (int i = 0; i < 16; ++i) {
      float4 v = p[i];
      int b = i * 4;
      acc = fmaf(v.x, h[b + 0], acc); acc = fmaf(v.y, h[b + 1], acc);
      acc = fmaf(v.z, h[b + 2], acc); acc = fmaf(v.w, h[b + 3], acc);
    }
  }
  return acc;
}

// =================== Kernel 1: hypernet MLPs, parallel-row layout ===========
// 320 threads (5 waves) per n: rows of all four first-layer mats computed in
// parallel segments, then all second-layer rows. 20 waves/CU vs 4 before.
template<int BF>
__device__ __forceinline__ void mlp_par(
    const void* states,
    const void* hw1_w1, const void* hw1_b1, const void* hw1_w2, const void* hw1_b2,
    const void* hb1_w,  const void* hb1_b,
    const void* hwf_w1, const void* hwf_b1, const void* hwf_w2, const void* hwf_b2,
    const void* v_w1,   const void* v_b1,   const void* v_w2,   const void* v_b2,
    float* w1_ws, float* b1_ws, float* wf_ws, float* v_ws,
    float* s_st, float* h1, float* hf, float* vh, int n, int tid)
{
  if (tid < 128) s_st[tid] = ldt<BF>(states, n * 128 + tid);
  __syncthreads();
  if (tid < 64)
    h1[tid] = fmaxf(dot128_t<BF>(hw1_w1, tid, s_st) + ldt<BF>(hw1_b1, tid), 0.f);
  else if (tid < 128)
    hf[tid - 64] = fmaxf(dot128_t<BF>(hwf_w1, tid - 64, s_st) + ldt<BF>(hwf_b1, tid - 64), 0.f);
  else if (tid < 160)
    vh[tid - 128] = fmaxf(dot128_t<BF>(v_w1, tid - 128, s_st) + ldt<BF>(v_b1, tid - 128), 0.f);
  else if (tid < 192)
    b1_ws[n * 32 + tid - 160] = dot128_t<BF>(hb1_w, tid - 160, s_st) + ldt<BF>(hb1_b, tid - 160);
  __syncthreads();
  if (tid < 256)
    w1_ws[n * 256 + tid] = fabsf(dot64_t<BF>(hw1_w2, tid, h1) + ldt<BF>(hw1_b2, tid));
  else if (tid < 288)
    wf_ws[n * 32 + tid - 256] = fabsf(dot64_t<BF>(hwf_w2, tid - 256, hf) + ldt<BF>(hwf_b2, tid - 256));
  else {
    int l2 = tid - 288;                      // wave 4, lanes 32..63
    float part = vh[l2] * ldt<BF>(v_w2, l2);
    part += __shfl_xor(part, 1);  part += __shfl_xor(part, 2);
    part += __shfl_xor(part, 4);  part += __shfl_xor(part, 8);
    part += __shfl_xor(part, 16);
    if (l2 == 0) v_ws[n] = part + ldt<BF>(v_b2, 0);
  }
}

__global__ __launch_bounds__(320) void k_mlp(
    const void* __restrict__ states,
    const void* __restrict__ hw1_w1, const void* __restrict__ hw1_b1,
    const void* __restrict__ hw1_w2, const void* __restrict__ hw1_b2,
    const void* __restrict__ hb1_w,  const void* __restrict__ hb1_b,
    const void* __restrict__ hwf_w1, const void* __restrict__ hwf_b1,
    const void* __restrict__ hwf_w2, const void* __restrict__ hwf_b2,
    const void* __restrict__ v_w1,   const void* __restrict__ v_b1,
    const void* __restrict__ v_w2,   const void* __restrict__ v_b2,
    float* __restrict__ w1_ws, float* __restrict__ b1_ws,
    float* __restrict__ wf_ws, float* __restrict__ v_ws,
    int* __restrict__ flag)
{
  __shared__ float s_st[128];
  __shared__ float h1[64], hf[64], vh[32];
  __shared__ int sh_flag;
  const int n = blockIdx.x;
  const int tid = threadIdx.x;

  // inline dtype detect (wave 0): first 128 u16 words of states (~N(0,1))
  if (tid < 64) {
    const u16* sr = (const u16*)states;
    unsigned int e0 = (sr[tid] >> 7) & 0xFF;
    unsigned int e1 = (sr[tid + 64] >> 7) & 0xFF;
    unsigned long long bl0 = __ballot(e0 >= 97 && e0 <= 141);
    unsigned long long bl1 = __ballot(e1 >= 97 && e1 <= 141);
    int bfv = (__popcll(bl0) + __popcll(bl1) >= 104) ? 1 : 0;
    if (tid == 0) { sh_flag = bfv; *flag = bfv; }   // all blocks same (benign)
  }
  __syncthreads();
  const int bf = sh_flag;

  if (bf)
    mlp_par<1>(states, hw1_w1, hw1_b1, hw1_w2, hw1_b2, hb1_w, hb1_b,
               hwf_w1, hwf_b1, hwf_w2, hwf_b2, v_w1, v_b1, v_w2, v_b2,
               w1_ws, b1_ws, wf_ws, v_ws, s_st, h1, hf, vh, n, tid);
  else
    mlp_par<0>(states, hw1_w1, hw1_b1, hw1_w2, hw1_b2, hb1_w, hb1_b,
               hwf_w1, hwf_b1, hwf_w2, hwf_b2, v_w1, v_b1, v_w2, v_b2,
               w1_ws, b1_ws, wf_ws, v_ws, s_st, h1, hf, vh, n, tid);
}

// ======= Kernel 2: 2 tasks per 128-thread block, one wave per task.
// Round-1 proven structure with surgical cuts:
//  - p_lds shared between the two tasks (same n), staged once + 1 barrier
//  - conv8 for span<=7 agents (typical case)
//  - elu projection via LDS atomicAdd (ds_add_f32) instead of segmented scan
//  - wf narrow case via strided 4-quarter gather + 2 shfl_xor
__global__ __launch_bounds__(128) void k_perembed(
    const void* __restrict__ aq,          // (1024, 8, 51)
    const float* __restrict__ w1_ws, const float* __restrict__ b1_ws,
    const float* __restrict__ wf_ws, float* __restrict__ xw_ws,
    const int* __restrict__ flag)
{
  __shared__ __align__(16) float P[8 * 52];     // probs (both tasks same n)
  __shared__ __align__(16) float TS[2][1332];   // per-task scratch
  // TS[w] layout: Ab 0..519 | Bb 520..1039 | kv 1040..1167 (8x16) |
  //               kvo 1168..1223 | x2 1224..1275 | g 1276..1328 (53)

  const int tid  = threadIdx.x;
  const int w    = tid >> 6;
  const int lane = tid & 63;
  const int task = blockIdx.x * 2 + w;
  const int n = task >> 5;
  const int e = task & 31;
  const int bf = *flag;

  // ---- stage probs (wave w loads rows 4w..4w+3; pad col 51 = 0) ----
  if (bf) {
    const u16* p = (const u16*)aq + n * 408;
    if (lane < 52) {
#pragma unroll
      for (int k = 0; k < 4; ++k) {
        int a = 4 * w + k;
        P[a * 52 + lane] = (lane < 51) ? bf2f(p[a * 51 + lane]) : 0.f;
      }
    }
  } else {
    const float* p = (const float*)aq + n * 408;
    if (lane < 52) {
#pragma unroll
      for (int k = 0; k < 4; ++k) {
        int a = 4 * w + k;
        P[a * 52 + lane] = (lane < 51) ? p[a * 51 + lane] : 0.f;
      }
    }
  }
  float wreg = (lane < 8) ? w1_ws[n * 256 + e * 8 + lane] : 0.f;
  float b1v  = b1_ws[n * 32 + e];
  float wfv  = wf_ws[n * 32 + e];

  int mlA = 0, mhA = 0;
  if (lane < 8) proj_bounds(wreg, mlA, mhA);
  __syncthreads();                       // ONE block barrier: P visible

  float* Ab  = TS[w];
  float* Bb  = Ab + 520;
  float* kv  = Ab + 1040;
  float* kvo = Ab + 1168;
  float* x2  = Ab + 1224;
  float* g   = Ab + 1276;

  // ---- narrow gathers: 2 rounds x (4 agents x 16 bins); T<=15 => no clamp --
#pragma unroll
  for (int r = 0; r < 2; ++r) {
    int a  = 4 * r + (lane >> 4);
    int jj = lane & 15;
    float wv = __shfl(wreg, a);
    int ML = __shfl(mlA, a);
    int MH = __shfl(mhA, a);
    int T  = MH - ML;
    float K = (25.0f - (float)(ML + jj)) - 25.0f * wv;
    float a0 = 0.f, a1 = 0.f, a2 = 0.f, a3 = 0.f;
    const float4* pb4 = (const float4*)(P + a * 52);
#pragma unroll
    for (int t4 = 0; t4 < 13; ++t4) {
      float4 p4 = pb4[t4];               // wave-uniform per 16-lane group
      float d0 = fmaf((float)(4 * t4 + 0), wv, K);
      float d1 = fmaf((float)(4 * t4 + 1), wv, K);
      float d2 = fmaf((float)(4 * t4 + 2), wv, K);
      float d3 = fmaf((float)(4 * t4 + 3), wv, K);
      a0 = fmaf(p4.x, fmaxf(0.f, 1.0f - fabsf(d0)), a0);
      a1 = fmaf(p4.y, fmaxf(0.f, 1.0f - fabsf(d1)), a1);
      a2 = fmaf(p4.z, fmaxf(0.f, 1.0f - fabsf(d2)), a2);
      a3 = fmaf(p4.w, fmaxf(0.f, 1.0f - fabsf(d3)), a3);
    }
    if (T <= 15)
      kv[a * 16 + jj] = (jj <= T) ? ((a0 + a1) + (a2 + a3)) : 0.f;
  }
  WAVE_SYNC();

  // ---- seed: agent 0 ----
  int LQ, HQ;
  float* q = Ab;
  float* qn = Bb;
  {
    float wv0 = __shfl(wreg, 0);
    int ML0 = __shfl(mlA, 0), MH0 = __shfl(mhA, 0);
    int T0 = MH0 - ML0;
    if (T0 <= 15) {
      if (lane <= T0) Ab[64 + ML0 + lane] = kv[lane];
    } else {
      float acc = gather_part<0, 13>(P, wv0, (float)(ML0 + lane));
      if (lane <= T0) Ab[64 + ML0 + lane] = acc;
    }
    WAVE_SYNC();
    LQ = 64 + ML0; HQ = 64 + MH0;
  }

  // ---- conv chain over agents 1..7 ----
  for (int a = 1; a < 8; ++a) {
    float wv = __shfl(wreg, a);
    int ML = __shfl(mlA, a), MH = __shfl(mhA, a);
    int T = MH - ML;
    const float* kvs;
    int W;
    if (T <= 15) {                       // wave-uniform branch
      kvs = kv + a * 16;
      W = (T <= 7) ? 8 : 16;
    } else {                             // rare wide agent
      float acc = gather_part<0, 13>(P + a * 52, wv, (float)(ML + lane));
      W = (T + 4) & ~3;                  // <= 52
      if (lane < W) kvo[lane] = (lane <= T) ? acc : 0.f;
      kvs = kvo;
    }
    if (lane < W - 1) q[LQ - 1 - lane] = 0.f;
    if (lane < T)     q[HQ + 1 + lane] = 0.f;
    WAVE_SYNC();
    if (T <= 7)       conv8 (q, qn, kvs, ML, T, LQ, HQ, lane, 64);
    else if (T <= 15) conv16(q, qn, kvs, ML, T, LQ, HQ, lane, 64);
    else              conv_pad2(q, qn, kvs, ML, W, T, LQ, HQ, lane, 64);
    WAVE_SYNC();
    LQ += ML; HQ += MH;
    float* t_ = q; q = qn; qn = t_;
  }

  // ---- elu projection via LDS atomicAdd (wave-local buffer) ----
  {
    if (lane < 53) g[lane] = 0.f;
    WAVE_SYNC();
    int span = HQ - LQ + 1;
    for (int base = 0; base < span; base += 64) {
      int t = base + lane;
      if (t < span) {
        int tg = (LQ - 64) + t;          // grid index in [0,400]
        float raw = (-80.0f + 0.4f * (float)tg) + b1v;
        float sup = (raw > 0.f) ? raw : expm1f(raw);
        float c  = fminf(fmaxf(sup, -10.0f), 10.0f);
        float b  = (c + 10.0f) / 0.4f;
        float l  = floorf(b);
        float u  = ceilf(b);
        float eq = (u == l) ? 1.0f : 0.0f;
        float p  = q[LQ + t];
        int   li = (int)l;
        atomicAdd(&g[li],     p * (u - b + eq));
        atomicAdd(&g[li + 1], p * (b - l));
      }
    }
    WAVE_SYNC();
  }
  if (lane < 52) x2[lane] = (lane < 51) ? g[lane] : 0.f;
  WAVE_SYNC();

  // ---- wf projection -> xw row ----
  {
    int MLf, MHf;
    proj_bounds(wfv, MLf, MHf);          // uniform across wave
    int Tf = MHf - MLf;
    if (Tf <= 15) {
      // strided split: lane = q4*16+jj gathers atoms t = q4+4k (no clamp:
      // wv<=~0.3 -> |sup|<=3); combine the 4 quarters with 2 shfl_xor.
      int q4 = lane >> 4, jj = lane & 15;
      float K = (25.0f - (float)(MLf + jj)) - 25.0f * wfv;
      float acc = 0.f;
#pragma unroll
      for (int k = 0; k < 13; ++k) {
        int t = q4 + 4 * k;
        float d = fmaf((float)t, wfv, K);
        acc = fmaf(x2[t], fmaxf(0.f, 1.0f - fabsf(d)), acc);
      }
      acc += __shfl_xor(acc, 16);
      acc += __shfl_xor(acc, 32);
      if (lane <= Tf)                    // Tf<=15 -> lanes 0..15, jj==lane
        xw_ws[task * 51 + MLf + lane] = acc;
    } else {
      float acc = gather_part<0, 13>(x2, wfv, (float)(MLf + lane));
      if (lane <= Tf)
        xw_ws[task * 51 + MLf + lane] = acc;
    }
  }
}

// ====== Kernel 3: TREE convolution — depth 5, 512 threads ======
__global__ __launch_bounds__(512) void k_final(
    const float* __restrict__ xw_ws, const float* __restrict__ wf_ws,
    const float* __restrict__ v_ws,
    void* __restrict__ out, const int* __restrict__ flag)
{
  __shared__ __align__(16) float bufA[4608];
  __shared__ __align__(16) float bufB[4608];
  __shared__ int meta_s[63];
  __shared__ int meta_l[63];
  __shared__ int meta_ml[32];
  __shared__ int meta_g[6];
  __shared__ int meta_mltot;
  __shared__ float gA[53];

  const int n    = blockIdx.x;
  const int tid  = threadIdx.x;
  const int lane = tid & 63;
  const int bf   = *flag;

  float vv = v_ws[n];

  for (int i = tid; i < 4608; i += 512) { bufA[i] = 0.f; bufB[i] = 0.f; }
  if (tid < 53) gA[tid] = 0.f;

  if (tid < 64) {
    float wfreg = (lane < 32) ? wf_ws[n * 32 + lane] : 0.f;
    int ml, mh;
    proj_bounds(wfreg, ml, mh);
    if (lane < 32) meta_ml[lane] = ml;
    int msum = ml;
#pragma unroll
    for (int d = 1; d < 32; d <<= 1) msum += __shfl_xor(msum, d);
    if (lane == 0) meta_mltot = msum;

    int curlen = mh - ml + 1;
    int base = 0, Ncur = 32;
#pragma unroll
    for (int c = 0; c <= 5; ++c) {
      int lm = (lane < Ncur) ? curlen : 0;
#pragma unroll
      for (int d = 1; d < 32; d <<= 1) {
        int o = __shfl_xor(lm, d);
        lm = (o > lm) ? o : lm;
      }
      int G = (lm + 11) & ~3;
      int sp = ((curlen + 3) & ~3) + G;
      int inc = (lane < Ncur) ? sp : 0;
      int v0 = inc;
#pragma unroll
      for (int d = 1; d < 32; d <<= 1) {
        int u = __shfl_up(inc, d);
        if (lane >= d && lane < 32) inc += u;
      }
      if (lane < Ncur) {
        meta_s[base + lane] = 832 + (inc - v0);
        meta_l[base + lane] = curlen;
      }
      if (lane == 0) meta_g[c] = G;
      if (c < 5) {
        int l0 = __shfl(curlen, 2 * lane);
        int l1 = __shfl(curlen, 2 * lane + 1);
        curlen = l0 + l1 - 1;
        base += Ncur;
        Ncur >>= 1;
      }
    }
  }
  __syncthreads();

  {
    int g = tid >> 4, i3 = tid & 15;     // 16 threads per embed row
    int s2 = meta_s[g], l2 = meta_l[g], ml = meta_ml[g];
    const float* row = xw_ws + (n * 32 + g) * 51 + ml;
    for (int i0 = i3; i0 < l2; i0 += 16) bufA[s2 + i0] = row[i0];
  }
  __syncthreads();

#pragma unroll
  for (int c = 1; c <= 5; ++c) {
    const float* bin = (c & 1) ? bufA : bufB;
    float*       bout = (c & 1) ? bufB : bufA;
    const int Nout = 32 >> c;
    const int lg = 4 + c;                // 512-thread split: gs*Nout == 512
    const int gs = 1 << lg;
    const int k  = tid >> lg;
    const int st = tid & (gs - 1);
    const int bc = 64 - (64 >> c);
    const int bp = 64 - (64 >> (c - 1));
    const int i0 = bp + 2 * k;
    const int sA = meta_s[i0];
    const int sB = meta_s[i0 + 1];
    const int lB = meta_l[i0 + 1];
    const int sO = meta_s[bc + k];
    const int lO = meta_l[bc + k];
    const int W  = (lB + 3) & ~3;

    for (int j = st * 2; j < lO; j += gs * 2) {
      const float* Ap = bin + sA + j + 1;
      float a0 = 0.f, a1 = 0.f;
      for (int m = 0; m < W; m += 4) {
        float4 k4 = *(const float4*)(bin + sB + m);
        float v0 = Ap[-m], v1 = Ap[-m - 1], v2 = Ap[-m - 2];
        float v3 = Ap[-m - 3], v4 = Ap[-m - 4];
        a0 = fmaf(k4.x, v1, fmaf(k4.y, v2, fmaf(k4.z, v3, fmaf(k4.w, v4, a0))));
        a1 = fmaf(k4.x, v0, fmaf(k4.y, v1, fmaf(k4.z, v2, fmaf(k4.w, v3, a1))));
      }
      bout[sO + j] = a0;
      if (j + 1 < lO) bout[sO + j + 1] = a1;
    }

    if (c >= 2 && c <= 4) {
      int G = meta_g[c];
      for (int p = tid; p < G; p += 512) bout[832 - G + p] = 0.f;
      for (int k2 = 0; k2 < Nout; ++k2) {
        int ss = meta_s[bc + k2] + meta_l[bc + k2];
        int ee = (k2 + 1 < Nout) ? meta_s[bc + k2 + 1]
                                 : ss + G + 3;
        for (int p = ss + tid; p < ee; p += 512) bout[p] = 0.f;
      }
    }
    __syncthreads();
  }

  // ---- final projection via LDS atomicAdd across all 512 threads ----
  {
    int s5 = meta_s[62], l5 = meta_l[62], mlt = meta_mltot;
    const float* qf = bufB + s5;
    for (int t = tid; t < l5; t += 512) {
      int tg = mlt + t;
      float sup = (-320.0f + 0.4f * (float)tg) + vv;
      float c  = fminf(fmaxf(sup, -10.0f), 10.0f);
      float b  = (c + 10.0f) / 0.4f;
      float l  = floorf(b);
      float u  = ceilf(b);
      float eq = (u == l) ? 1.0f : 0.0f;
      float p  = qf[t];
      int   li = (int)l;
      atomicAdd(&gA[li],     p * (u - b + eq));
      atomicAdd(&gA[li + 1], p * (b - l));
    }
  }
  __syncthreads();
  if (tid < 51) {
    float o = gA[tid];
    if (bf) ((u16*)out)[n * 51 + tid] = f2bf(o);
    else    ((float*)out)[n * 51 + tid] = o;
  }
}

// =========================== launcher ===========================
extern "C" void kernel_launch(void* const* d_in, const int* in_sizes, int n_in,
                              void* d_out, int out_size, void* d_ws, size_t ws_size,
                              hipStream_t stream)
{
  float* ws    = (float*)d_ws;
  float* w1_ws = ws;                       // 1024*256
  float* b1_ws = w1_ws + 1024 * 256;       // 1024*32
  float* wf_ws = b1_ws + 1024 * 32;        // 1024*32
  float* v_ws  = wf_ws + 1024 * 32;        // 1024
  float* xw_ws = v_ws  + 1024;             // 1024*32*51
  int*   flag  = (int*)(xw_ws + 1024 * 32 * 51);

  k_mlp<<<1024, 320, 0, stream>>>(d_in[1],
      d_in[2], d_in[3], d_in[4], d_in[5], d_in[6], d_in[7],
      d_in[8], d_in[9], d_in[10], d_in[11], d_in[12], d_in[13],
      d_in[14], d_in[15],
      w1_ws, b1_ws, wf_ws, v_ws, flag);

  k_perembed<<<16384, 128, 0, stream>>>(d_in[0], w1_ws, b1_ws, wf_ws, xw_ws, flag);

  k_final<<<1024, 512, 0, stream>>>(xw_ws, wf_ws, v_ws, d_out, flag);
}

// Round 5
// 251.845 us; speedup vs baseline: 1.3264x; 1.0118x over previous
//
#include <hip/hip_runtime.h>
#include <hip/hip_bf16.h>
#include <math.h>

typedef unsigned short u16;

// Wave-local LDS drain (same-wave DS ops execute in order; this also fences
// the compiler).
#define WAVE_SYNC() asm volatile("s_waitcnt lgkmcnt(0)" ::: "memory")

// ---------- dtype helpers ----------
__device__ __forceinline__ float bf2f(u16 u) {
  union { unsigned int i; float f; } c;
  c.i = ((unsigned int)u) << 16;
  return c.f;
}
__device__ __forceinline__ float bflo(unsigned int u) {
  union { unsigned int i; float f; } c; c.i = u << 16; return c.f;
}
__device__ __forceinline__ float bfhi(unsigned int u) {
  union { unsigned int i; float f; } c; c.i = u & 0xffff0000u; return c.f;
}
__device__ __forceinline__ u16 f2bf(float f) {
  union { float f; unsigned int i; } c;
  c.f = f;
  unsigned int x = c.i;
  unsigned int r = (x + 0x7fffu + ((x >> 16) & 1u)) >> 16; // RNE
  return (u16)r;
}

// Destination-bin bounds for proj of supports (-10+0.4t)*wv, t=0..50, wv>=0.
__device__ __forceinline__ void proj_bounds(float wv, int& ML, int& MH) {
  float smin = (-10.0f + 0.4f * 0.0f)  * wv;
  float smax = (-10.0f + 0.4f * 50.0f) * wv;
  float bmin = (fminf(fmaxf(smin, -10.0f), 10.0f) + 10.0f) / 0.4f;
  float bmax = (fminf(fmaxf(smax, -10.0f), 10.0f) + 10.0f) / 0.4f;
  ML = (int)floorf(bmin);
  MH = (int)ceilf(bmax);
}

// ---------- runtime-width convolution (wide agents only) --------------------
__device__ __forceinline__ void conv_pad2(const float* __restrict__ q,
                                          float* __restrict__ qn,
                                          const float* __restrict__ kvs,
                                          int ML, int W, int T,
                                          int LQ, int HQ, int tid, int nthr)
{
  const int Lout = LQ + ML, Hout = HQ + ML + T;
  for (int J = Lout + tid; J <= Hout; J += nthr) {
    const float* qp = q + (J - ML);
    float acc = 0.f;
    for (int c = 0; c < W; c += 4) {
      float4 k4 = *(const float4*)(kvs + c);   // uniform address -> broadcast
      acc = fmaf(k4.x, qp[-c],     acc);
      acc = fmaf(k4.y, qp[-c - 1], acc);
      acc = fmaf(k4.z, qp[-c - 2], acc);
      acc = fmaf(k4.w, qp[-c - 3], acc);
    }
    qn[J] = acc;
  }
}

// ---------- fixed-tap fully-unrolled convolutions (narrow agents) -----------
__device__ __forceinline__ void conv16(const float* __restrict__ q,
                                       float* __restrict__ qn,
                                       const float* __restrict__ kvs,
                                       int ML, int T,
                                       int LQ, int HQ, int tid, int nthr)
{
  const int Lout = LQ + ML, Hout = HQ + ML + T;
  for (int J = Lout + tid; J <= Hout; J += nthr) {
    const float* qp = q + (J - ML);
    float a0 = 0.f, a1 = 0.f;
#pragma unroll
    for (int c = 0; c < 16; c += 4) {
      float4 k4 = *(const float4*)(kvs + c);   // uniform -> broadcast
      a0 = fmaf(k4.x, qp[-c],     a0);
      a1 = fmaf(k4.y, qp[-c - 1], a1);
      a0 = fmaf(k4.z, qp[-c - 2], a0);
      a1 = fmaf(k4.w, qp[-c - 3], a1);
    }
    qn[J] = a0 + a1;
  }
}

__device__ __forceinline__ void conv8(const float* __restrict__ q,
                                      float* __restrict__ qn,
                                      const float* __restrict__ kvs,
                                      int ML, int T,
                                      int LQ, int HQ, int tid, int nthr)
{
  const int Lout = LQ + ML, Hout = HQ + ML + T;
  for (int J = Lout + tid; J <= Hout; J += nthr) {
    const float* qp = q + (J - ML);
    float a0 = 0.f, a1 = 0.f;
#pragma unroll
    for (int c = 0; c < 8; c += 4) {
      float4 k4 = *(const float4*)(kvs + c);   // uniform -> broadcast
      a0 = fmaf(k4.x, qp[-c],     a0);
      a1 = fmaf(k4.y, qp[-c - 1], a1);
      a0 = fmaf(k4.z, qp[-c - 2], a0);
      a1 = fmaf(k4.w, qp[-c - 3], a1);
    }
    qn[J] = a0 + a1;
  }
}

// ---------- all-atom gather with clamp (wide agents / wide wf) --------------
template<int TA, int TB>
__device__ __forceinline__ float gather_part(const float* __restrict__ pb,
                                             float wv, float j)
{
  float a0 = 0.f, a1 = 0.f, a2 = 0.f, a3 = 0.f;
  const float4* pb4 = (const float4*)pb;
  const float base = 25.0f - j;
#pragma unroll
  for (int t4 = TA; t4 < TB; ++t4) {
    float4 p4 = pb4[t4];
#define G1(PX, TT, AC) { \
    float sup = ((float)(TT) * 0.4f - 10.0f) * wv; \
    float c   = fminf(fmaxf(sup, -10.0f), 10.0f); \
    float d   = fmaf(c, 2.5f, base); \
    AC = fmaf(PX, fmaxf(0.f, 1.0f - fabsf(d)), AC); }
    G1(p4.x, 4 * t4 + 0, a0)
    G1(p4.y, 4 * t4 + 1, a1)
    G1(p4.z, 4 * t4 + 2, a2)
    G1(p4.w, 4 * t4 + 3, a3)
#undef G1
  }
  return (a0 + a1) + (a2 + a3);
}

// ---------- typed loads / dot rows ----------
template<int BF>
__device__ __forceinline__ float ldt(const void* p, int i) {
  if (BF) return bf2f(((const u16*)p)[i]);
  return ((const float*)p)[i];
}

template<int BF>
__device__ __forceinline__ float dot128_t(const void* w, int row, const float* s) {
  float acc = 0.f;
  if (BF) {
    const uint4* p = (const uint4*)((const u16*)w + row * 128);
#pragma unroll
    for (int i = 0; i < 16; ++i) {
      uint4 v = p[i];
      int b = i * 8;
      acc = fmaf(bflo(v.x), s[b + 0], acc); acc = fmaf(bfhi(v.x), s[b + 1], acc);
      acc = fmaf(bflo(v.y), s[b + 2], acc); acc = fmaf(bfhi(v.y), s[b + 3], acc);
      acc = fmaf(bflo(v.z), s[b + 4], acc); acc = fmaf(bfhi(v.z), s[b + 5], acc);
      acc = fmaf(bflo(v.w), s[b + 6], acc); acc = fmaf(bfhi(v.w), s[b + 7], acc);
    }
  } else {
    const float4* p = (const float4*)((const float*)w + row * 128);
#pragma unroll
    for (int i = 0; i < 32; ++i) {
      float4 v = p[i];
      int b = i * 4;
      acc = fmaf(v.x, s[b + 0], acc); acc = fmaf(v.y, s[b + 1], acc);
      acc = fmaf(v.z, s[b + 2], acc); acc = fmaf(v.w, s[b + 3], acc);
    }
  }
  return acc;
}

template<int BF>
__device__ __forceinline__ float dot64_t(const void* w, int row, const float* h) {
  float acc = 0.f;
  if (BF) {
    const uint4* p = (const uint4*)((const u16*)w + row * 64);
#pragma unroll
    for (int i = 0; i < 8; ++i) {
      uint4 v = p[i];
      int b = i * 8;
      acc = fmaf(bflo(v.x), h[b + 0], acc); acc = fmaf(bfhi(v.x), h[b + 1], acc);
      acc = fmaf(bflo(v.y), h[b + 2], acc); acc = fmaf(bfhi(v.y), h[b + 3], acc);
      acc = fmaf(bflo(v.z), h[b + 4], acc); acc = fmaf(bfhi(v.z), h[b + 5], acc);
      acc = fmaf(bflo(v.w), h[b + 6], acc); acc = fmaf(bfhi(v.w), h[b + 7], acc);
    }
  } else {
    const float4* p = (const float4*)((const float*)w + row * 64);
#pragma unroll
    for (int i = 0; i < 16; ++i) {
      float4 v = p[i];
      int b = i * 4;
      acc = fmaf(v.x, h[b + 0], acc); acc = fmaf(v.y, h[b + 1], acc);
      acc = fmaf(v.z, h[b + 2], acc); acc = fmaf(v.w, h[b + 3], acc);
    }
  }
  return acc;
}

// =================== Kernel 1: hypernet MLPs, parallel-row layout ===========
template<int BF>
__device__ __forceinline__ void mlp_par(
    const void* states,
    const void* hw1_w1, const void* hw1_b1, const void* hw1_w2, const void* hw1_b2,
    const void* hb1_w,  const void* hb1_b,
    const void* hwf_w1, const void* hwf_b1, const void* hwf_w2, const void* hwf_b2,
    const void* v_w1,   const void* v_b1,   const void* v_w2,   const void* v_b2,
    float* w1_ws, float* b1_ws, float* wf_ws, float* v_ws,
    float* s_st, float* h1, float* hf, float* vh, int n, int tid)
{
  if (tid < 128) s_st[tid] = ldt<BF>(states, n * 128 + tid);
  __syncthreads();
  if (tid < 64)
    h1[tid] = fmaxf(dot128_t<BF>(hw1_w1, tid, s_st) + ldt<BF>(hw1_b1, tid), 0.f);
  else if (tid < 128)
    hf[tid - 64] = fmaxf(dot128_t<BF>(hwf_w1, tid - 64, s_st) + ldt<BF>(hwf_b1, tid - 64), 0.f);
  else if (tid < 160)
    vh[tid - 128] = fmaxf(dot128_t<BF>(v_w1, tid - 128, s_st) + ldt<BF>(v_b1, tid - 128), 0.f);
  else if (tid < 192)
    b1_ws[n * 32 + tid - 160] = dot128_t<BF>(hb1_w, tid - 160, s_st) + ldt<BF>(hb1_b, tid - 160);
  __syncthreads();
  if (tid < 256)
    w1_ws[n * 256 + tid] = fabsf(dot64_t<BF>(hw1_w2, tid, h1) + ldt<BF>(hw1_b2, tid));
  else if (tid < 288)
    wf_ws[n * 32 + tid - 256] = fabsf(dot64_t<BF>(hwf_w2, tid - 256, hf) + ldt<BF>(hwf_b2, tid - 256));
  else {
    int l2 = tid - 288;                      // wave 4, lanes 32..63
    float part = vh[l2] * ldt<BF>(v_w2, l2);
    part += __shfl_xor(part, 1);  part += __shfl_xor(part, 2);
    part += __shfl_xor(part, 4);  part += __shfl_xor(part, 8);
    part += __shfl_xor(part, 16);
    if (l2 == 0) v_ws[n] = part + ldt<BF>(v_b2, 0);
  }
}

__global__ __launch_bounds__(320) void k_mlp(
    const void* __restrict__ states,
    const void* __restrict__ hw1_w1, const void* __restrict__ hw1_b1,
    const void* __restrict__ hw1_w2, const void* __restrict__ hw1_b2,
    const void* __restrict__ hb1_w,  const void* __restrict__ hb1_b,
    const void* __restrict__ hwf_w1, const void* __restrict__ hwf_b1,
    const void* __restrict__ hwf_w2, const void* __restrict__ hwf_b2,
    const void* __restrict__ v_w1,   const void* __restrict__ v_b1,
    const void* __restrict__ v_w2,   const void* __restrict__ v_b2,
    float* __restrict__ w1_ws, float* __restrict__ b1_ws,
    float* __restrict__ wf_ws, float* __restrict__ v_ws,
    int* __restrict__ flag)
{
  __shared__ float s_st[128];
  __shared__ float h1[64], hf[64], vh[32];
  __shared__ int sh_flag;
  const int n = blockIdx.x;
  const int tid = threadIdx.x;

  // inline dtype detect (wave 0): first 128 u16 words of states (~N(0,1))
  if (tid < 64) {
    const u16* sr = (const u16*)states;
    unsigned int e0 = (sr[tid] >> 7) & 0xFF;
    unsigned int e1 = (sr[tid + 64] >> 7) & 0xFF;
    unsigned long long bl0 = __ballot(e0 >= 97 && e0 <= 141);
    unsigned long long bl1 = __ballot(e1 >= 97 && e1 <= 141);
    int bfv = (__popcll(bl0) + __popcll(bl1) >= 104) ? 1 : 0;
    if (tid == 0) { sh_flag = bfv; *flag = bfv; }   // all blocks same (benign)
  }
  __syncthreads();
  const int bf = sh_flag;

  if (bf)
    mlp_par<1>(states, hw1_w1, hw1_b1, hw1_w2, hw1_b2, hb1_w, hb1_b,
               hwf_w1, hwf_b1, hwf_w2, hwf_b2, v_w1, v_b1, v_w2, v_b2,
               w1_ws, b1_ws, wf_ws, v_ws, s_st, h1, hf, vh, n, tid);
  else
    mlp_par<0>(states, hw1_w1, hw1_b1, hw1_w2, hw1_b2, hb1_w, hb1_b,
               hwf_w1, hwf_b1, hwf_w2, hwf_b2, v_w1, v_b1, v_w2, v_b2,
               w1_ws, b1_ws, wf_ws, v_ws, s_st, h1, hf, vh, n, tid);
}

// ======= Kernel 2: ONE task per 64-thread block (1 wave = 1 WG).
// Finest scheduling granularity: no intra-block barriers at all (pure
// WAVE_SYNC), ~7 KB LDS/block (22 blocks/CU by LDS). Isolates the
// occupancy lever; compute structure identical to Round 4.
__global__ __launch_bounds__(64) void k_perembed(
    const void* __restrict__ aq,          // (1024, 8, 51)
    const float* __restrict__ w1_ws, const float* __restrict__ b1_ws,
    const float* __restrict__ wf_ws, float* __restrict__ xw_ws,
    const int* __restrict__ flag)
{
  __shared__ __align__(16) float P[416];      // 8 x 52 probs (pad col 51 = 0)
  __shared__ __align__(16) float TS[1332];    // task scratch
  // TS layout: Ab 0..519 | Bb 520..1039 | kv 1040..1167 (8x16) |
  //            kvo 1168..1223 | x2 1224..1275 | g 1276..1328 (53)

  const int lane = threadIdx.x;
  const int task = blockIdx.x;
  const int n = task >> 5;
  const int e = task & 31;
  const int bf = *flag;

  // issue scalar params first so their latency overlaps staging
  float wreg = (lane < 8) ? w1_ws[n * 256 + e * 8 + lane] : 0.f;
  float b1v  = b1_ws[n * 32 + e];
  float wfv  = wf_ws[n * 32 + e];

  // ---- stage probs (single wave loads all 8 rows) ----
  if (bf) {
    const u16* p = (const u16*)aq + n * 408;
    if (lane < 52) {
#pragma unroll
      for (int a = 0; a < 8; ++a)
        P[a * 52 + lane] = (lane < 51) ? bf2f(p[a * 51 + lane]) : 0.f;
    }
  } else {
    const float* p = (const float*)aq + n * 408;
    if (lane < 52) {
#pragma unroll
      for (int a = 0; a < 8; ++a)
        P[a * 52 + lane] = (lane < 51) ? p[a * 51 + lane] : 0.f;
    }
  }

  int mlA = 0, mhA = 0;
  if (lane < 8) proj_bounds(wreg, mlA, mhA);
  WAVE_SYNC();                           // P visible to this wave

  float* Ab  = TS;
  float* Bb  = TS + 520;
  float* kv  = TS + 1040;
  float* kvo = TS + 1168;
  float* x2  = TS + 1224;
  float* g   = TS + 1276;

  // ---- narrow gathers: 2 rounds x (4 agents x 16 bins); T<=15 => no clamp --
#pragma unroll
  for (int r = 0; r < 2; ++r) {
    int a  = 4 * r + (lane >> 4);
    int jj = lane & 15;
    float wv = __shfl(wreg, a);
    int ML = __shfl(mlA, a);
    int MH = __shfl(mhA, a);
    int T  = MH - ML;
    float K = (25.0f - (float)(ML + jj)) - 25.0f * wv;
    float a0 = 0.f, a1 = 0.f, a2 = 0.f, a3 = 0.f;
    const float4* pb4 = (const float4*)(P + a * 52);
#pragma unroll
    for (int t4 = 0; t4 < 13; ++t4) {
      float4 p4 = pb4[t4];               // wave-uniform per 16-lane group
      float d0 = fmaf((float)(4 * t4 + 0), wv, K);
      float d1 = fmaf((float)(4 * t4 + 1), wv, K);
      float d2 = fmaf((float)(4 * t4 + 2), wv, K);
      float d3 = fmaf((float)(4 * t4 + 3), wv, K);
      a0 = fmaf(p4.x, fmaxf(0.f, 1.0f - fabsf(d0)), a0);
      a1 = fmaf(p4.y, fmaxf(0.f, 1.0f - fabsf(d1)), a1);
      a2 = fmaf(p4.z, fmaxf(0.f, 1.0f - fabsf(d2)), a2);
      a3 = fmaf(p4.w, fmaxf(0.f, 1.0f - fabsf(d3)), a3);
    }
    if (T <= 15)
      kv[a * 16 + jj] = (jj <= T) ? ((a0 + a1) + (a2 + a3)) : 0.f;
  }
  WAVE_SYNC();

  // ---- seed: agent 0 ----
  int LQ, HQ;
  float* q = Ab;
  float* qn = Bb;
  {
    float wv0 = __shfl(wreg, 0);
    int ML0 = __shfl(mlA, 0), MH0 = __shfl(mhA, 0);
    int T0 = MH0 - ML0;
    if (T0 <= 15) {
      if (lane <= T0) Ab[64 + ML0 + lane] = kv[lane];
    } else {
      float acc = gather_part<0, 13>(P, wv0, (float)(ML0 + lane));
      if (lane <= T0) Ab[64 + ML0 + lane] = acc;
    }
    WAVE_SYNC();
    LQ = 64 + ML0; HQ = 64 + MH0;
  }

  // ---- conv chain over agents 1..7 ----
  for (int a = 1; a < 8; ++a) {
    float wv = __shfl(wreg, a);
    int ML = __shfl(mlA, a), MH = __shfl(mhA, a);
    int T = MH - ML;
    const float* kvs;
    int W;
    if (T <= 15) {                       // wave-uniform branch
      kvs = kv + a * 16;
      W = (T <= 7) ? 8 : 16;
    } else {                             // rare wide agent
      float acc = gather_part<0, 13>(P + a * 52, wv, (float)(ML + lane));
      W = (T + 4) & ~3;                  // <= 52
      if (lane < W) kvo[lane] = (lane <= T) ? acc : 0.f;
      kvs = kvo;
    }
    if (lane < W - 1) q[LQ - 1 - lane] = 0.f;
    if (lane < T)     q[HQ + 1 + lane] = 0.f;
    WAVE_SYNC();
    if (T <= 7)       conv8 (q, qn, kvs, ML, T, LQ, HQ, lane, 64);
    else if (T <= 15) conv16(q, qn, kvs, ML, T, LQ, HQ, lane, 64);
    else              conv_pad2(q, qn, kvs, ML, W, T, LQ, HQ, lane, 64);
    WAVE_SYNC();
    LQ += ML; HQ += MH;
    float* t_ = q; q = qn; qn = t_;
  }

  // ---- elu projection via LDS atomicAdd (wave-local buffer) ----
  {
    if (lane < 53) g[lane] = 0.f;
    WAVE_SYNC();
    int span = HQ - LQ + 1;
    for (int base = 0; base < span; base += 64) {
      int t = base + lane;
      if (t < span) {
        int tg = (LQ - 64) + t;          // grid index in [0,400]
        float raw = (-80.0f + 0.4f * (float)tg) + b1v;
        float sup = (raw > 0.f) ? raw : expm1f(raw);
        float c  = fminf(fmaxf(sup, -10.0f), 10.0f);
        float b  = (c + 10.0f) / 0.4f;
        float l  = floorf(b);
        float u  = ceilf(b);
        float eq = (u == l) ? 1.0f : 0.0f;
        float p  = q[LQ + t];
        int   li = (int)l;
        atomicAdd(&g[li],     p * (u - b + eq));
        atomicAdd(&g[li + 1], p * (b - l));
      }
    }
    WAVE_SYNC();
  }
  if (lane < 52) x2[lane] = (lane < 51) ? g[lane] : 0.f;
  WAVE_SYNC();

  // ---- wf projection -> xw row ----
  {
    int MLf, MHf;
    proj_bounds(wfv, MLf, MHf);          // uniform across wave
    int Tf = MHf - MLf;
    if (Tf <= 15) {
      // strided split: lane = q4*16+jj gathers atoms t = q4+4k (no clamp:
      // wv<=~0.3 -> |sup|<=3); combine the 4 quarters with 2 shfl_xor.
      int q4 = lane >> 4, jj = lane & 15;
      float K = (25.0f - (float)(MLf + jj)) - 25.0f * wfv;
      float acc = 0.f;
#pragma unroll
      for (int k = 0; k < 13; ++k) {
        int t = q4 + 4 * k;
        float d = fmaf((float)t, wfv, K);
        acc = fmaf(x2[t], fmaxf(0.f, 1.0f - fabsf(d)), acc);
      }
      acc += __shfl_xor(acc, 16);
      acc += __shfl_xor(acc, 32);
      if (lane <= Tf)                    // Tf<=15 -> lanes 0..15, jj==lane
        xw_ws[task * 51 + MLf + lane] = acc;
    } else {
      float acc = gather_part<0, 13>(x2, wfv, (float)(MLf + lane));
      if (lane <= Tf)
        xw_ws[task * 51 + MLf + lane] = acc;
    }
  }
}

// ====== Kernel 3: TREE convolution — depth 5, 512 threads ======
__global__ __launch_bounds__(512) void k_final(
    const float* __restrict__ xw_ws, const float* __restrict__ wf_ws,
    const float* __restrict__ v_ws,
    void* __restrict__ out, const int* __restrict__ flag)
{
  __shared__ __align__(16) float bufA[4608];
  __shared__ __align__(16) float bufB[4608];
  __shared__ int meta_s[63];
  __shared__ int meta_l[63];
  __shared__ int meta_ml[32];
  __shared__ int meta_g[6];
  __shared__ int meta_mltot;
  __shared__ float gA[53];

  const int n    = blockIdx.x;
  const int tid  = threadIdx.x;
  const int lane = tid & 63;
  const int bf   = *flag;

  float vv = v_ws[n];

  for (int i = tid; i < 4608; i += 512) { bufA[i] = 0.f; bufB[i] = 0.f; }
  if (tid < 53) gA[tid] = 0.f;

  if (tid < 64) {
    float wfreg = (lane < 32) ? wf_ws[n * 32 + lane] : 0.f;
    int ml, mh;
    proj_bounds(wfreg, ml, mh);
    if (lane < 32) meta_ml[lane] = ml;
    int msum = ml;
#pragma unroll
    for (int d = 1; d < 32; d <<= 1) msum += __shfl_xor(msum, d);
    if (lane == 0) meta_mltot = msum;

    int curlen = mh - ml + 1;
    int base = 0, Ncur = 32;
#pragma unroll
    for (int c = 0; c <= 5; ++c) {
      int lm = (lane < Ncur) ? curlen : 0;
#pragma unroll
      for (int d = 1; d < 32; d <<= 1) {
        int o = __shfl_xor(lm, d);
        lm = (o > lm) ? o : lm;
      }
      int G = (lm + 11) & ~3;
      int sp = ((curlen + 3) & ~3) + G;
      int inc = (lane < Ncur) ? sp : 0;
      int v0 = inc;
#pragma unroll
      for (int d = 1; d < 32; d <<= 1) {
        int u = __shfl_up(inc, d);
        if (lane >= d && lane < 32) inc += u;
      }
      if (lane < Ncur) {
        meta_s[base + lane] = 832 + (inc - v0);
        meta_l[base + lane] = curlen;
      }
      if (lane == 0) meta_g[c] = G;
      if (c < 5) {
        int l0 = __shfl(curlen, 2 * lane);
        int l1 = __shfl(curlen, 2 * lane + 1);
        curlen = l0 + l1 - 1;
        base += Ncur;
        Ncur >>= 1;
      }
    }
  }
  __syncthreads();

  {
    int g = tid >> 4, i3 = tid & 15;     // 16 threads per embed row
    int s2 = meta_s[g], l2 = meta_l[g], ml = meta_ml[g];
    const float* row = xw_ws + (n * 32 + g) * 51 + ml;
    for (int i0 = i3; i0 < l2; i0 += 16) bufA[s2 + i0] = row[i0];
  }
  __syncthreads();

#pragma unroll
  for (int c = 1; c <= 5; ++c) {
    const float* bin = (c & 1) ? bufA : bufB;
    float*       bout = (c & 1) ? bufB : bufA;
    const int Nout = 32 >> c;
    const int lg = 4 + c;                // 512-thread split: gs*Nout == 512
    const int gs = 1 << lg;
    const int k  = tid >> lg;
    const int st = tid & (gs - 1);
    const int bc = 64 - (64 >> c);
    const int bp = 64 - (64 >> (c - 1));
    const int i0 = bp + 2 * k;
    const int sA = meta_s[i0];
    const int sB = meta_s[i0 + 1];
    const int lB = meta_l[i0 + 1];
    const int sO = meta_s[bc + k];
    const int lO = meta_l[bc + k];
    const int W  = (lB + 3) & ~3;

    for (int j = st * 2; j < lO; j += gs * 2) {
      const float* Ap = bin + sA + j + 1;
      float a0 = 0.f, a1 = 0.f;
      for (int m = 0; m < W; m += 4) {
        float4 k4 = *(const float4*)(bin + sB + m);
        float v0 = Ap[-m], v1 = Ap[-m - 1], v2 = Ap[-m - 2];
        float v3 = Ap[-m - 3], v4 = Ap[-m - 4];
        a0 = fmaf(k4.x, v1, fmaf(k4.y, v2, fmaf(k4.z, v3, fmaf(k4.w, v4, a0))));
        a1 = fmaf(k4.x, v0, fmaf(k4.y, v1, fmaf(k4.z, v2, fmaf(k4.w, v3, a1))));
      }
      bout[sO + j] = a0;
      if (j + 1 < lO) bout[sO + j + 1] = a1;
    }

    if (c >= 2 && c <= 4) {
      int G = meta_g[c];
      for (int p = tid; p < G; p += 512) bout[832 - G + p] = 0.f;
      for (int k2 = 0; k2 < Nout; ++k2) {
        int ss = meta_s[bc + k2] + meta_l[bc + k2];
        int ee = (k2 + 1 < Nout) ? meta_s[bc + k2 + 1]
                                 : ss + G + 3;
        for (int p = ss + tid; p < ee; p += 512) bout[p] = 0.f;
      }
    }
    __syncthreads();
  }

  // ---- final projection via LDS atomicAdd across all 512 threads ----
  {
    int s5 = meta_s[62], l5 = meta_l[62], mlt = meta_mltot;
    const float* qf = bufB + s5;
    for (int t = tid; t < l5; t += 512) {
      int tg = mlt + t;
      float sup = (-320.0f + 0.4f * (float)tg) + vv;
      float c  = fminf(fmaxf(sup, -10.0f), 10.0f);
      float b  = (c + 10.0f) / 0.4f;
      float l  = floorf(b);
      float u  = ceilf(b);
      float eq = (u == l) ? 1.0f : 0.0f;
      float p  = qf[t];
      int   li = (int)l;
      atomicAdd(&gA[li],     p * (u - b + eq));
      atomicAdd(&gA[li + 1], p * (b - l));
    }
  }
  __syncthreads();
  if (tid < 51) {
    float o = gA[tid];
    if (bf) ((u16*)out)[n * 51 + tid] = f2bf(o);
    else    ((float*)out)[n * 51 + tid] = o;
  }
}

// =========================== launcher ===========================
extern "C" void kernel_launch(void* const* d_in, const int* in_sizes, int n_in,
                              void* d_out, int out_size, void* d_ws, size_t ws_size,
                              hipStream_t stream)
{
  float* ws    = (float*)d_ws;
  float* w1_ws = ws;                       // 1024*256
  float* b1_ws = w1_ws + 1024 * 256;       // 1024*32
  float* wf_ws = b1_ws + 1024 * 32;        // 1024*32
  float* v_ws  = wf_ws + 1024 * 32;        // 1024
  float* xw_ws = v_ws  + 1024;             // 1024*32*51
  int*   flag  = (int*)(xw_ws + 1024 * 32 * 51);

  k_mlp<<<1024, 320, 0, stream>>>(d_in[1],
      d_in[2], d_in[3], d_in[4], d_in[5], d_in[6], d_in[7],
      d_in[8], d_in[9], d_in[10], d_in[11], d_in[12], d_in[13],
      d_in[14], d_in[15],
      w1_ws, b1_ws, wf_ws, v_ws, flag);

  k_perembed<<<32768, 64, 0, stream>>>(d_in[0], w1_ws, b1_ws, wf_ws, xw_ws, flag);

  k_final<<<1024, 512, 0, stream>>>(xw_ws, wf_ws, v_ws, d_out, flag);
}

// Round 6
// 251.616 us; speedup vs baseline: 1.3277x; 1.0009x over previous
//
#include <hip/hip_runtime.h>
#include <hip/hip_bf16.h>
#include <math.h>

typedef unsigned short u16;

// Wave-local LDS drain (same-wave DS ops execute in order; this also fences
// the compiler).
#define WAVE_SYNC() asm volatile("s_waitcnt lgkmcnt(0)" ::: "memory")

// ---------- dtype helpers ----------
__device__ __forceinline__ float bf2f(u16 u) {
  union { unsigned int i; float f; } c;
  c.i = ((unsigned int)u) << 16;
  return c.f;
}
__device__ __forceinline__ float bflo(unsigned int u) {
  union { unsigned int i; float f; } c; c.i = u << 16; return c.f;
}
__device__ __forceinline__ float bfhi(unsigned int u) {
  union { unsigned int i; float f; } c; c.i = u & 0xffff0000u; return c.f;
}
__device__ __forceinline__ u16 f2bf(float f) {
  union { float f; unsigned int i; } c;
  c.f = f;
  unsigned int x = c.i;
  unsigned int r = (x + 0x7fffu + ((x >> 16) & 1u)) >> 16; // RNE
  return (u16)r;
}

// Destination-bin bounds for proj of supports (-10+0.4t)*wv, t=0..50, wv>=0.
__device__ __forceinline__ void proj_bounds(float wv, int& ML, int& MH) {
  float smin = (-10.0f + 0.4f * 0.0f)  * wv;
  float smax = (-10.0f + 0.4f * 50.0f) * wv;
  float bmin = (fminf(fmaxf(smin, -10.0f), 10.0f) + 10.0f) / 0.4f;
  float bmax = (fminf(fmaxf(smax, -10.0f), 10.0f) + 10.0f) / 0.4f;
  ML = (int)floorf(bmin);
  MH = (int)ceilf(bmax);
}

// ---------- runtime-width convolution (wide agents only) --------------------
__device__ __forceinline__ void conv_pad2(const float* __restrict__ q,
                                          float* __restrict__ qn,
                                          const float* __restrict__ kvs,
                                          int ML, int W, int T,
                                          int LQ, int HQ, int tid, int nthr)
{
  const int Lout = LQ + ML, Hout = HQ + ML + T;
  for (int J = Lout + tid; J <= Hout; J += nthr) {
    const float* qp = q + (J - ML);
    float acc = 0.f;
    for (int c = 0; c < W; c += 4) {
      float4 k4 = *(const float4*)(kvs + c);   // uniform address -> broadcast
      acc = fmaf(k4.x, qp[-c],     acc);
      acc = fmaf(k4.y, qp[-c - 1], acc);
      acc = fmaf(k4.z, qp[-c - 2], acc);
      acc = fmaf(k4.w, qp[-c - 3], acc);
    }
    qn[J] = acc;
  }
}

// ---------- fixed-tap fully-unrolled convolutions (narrow agents) -----------
__device__ __forceinline__ void conv16(const float* __restrict__ q,
                                       float* __restrict__ qn,
                                       const float* __restrict__ kvs,
                                       int ML, int T,
                                       int LQ, int HQ, int tid, int nthr)
{
  const int Lout = LQ + ML, Hout = HQ + ML + T;
  for (int J = Lout + tid; J <= Hout; J += nthr) {
    const float* qp = q + (J - ML);
    float a0 = 0.f, a1 = 0.f;
#pragma unroll
    for (int c = 0; c < 16; c += 4) {
      float4 k4 = *(const float4*)(kvs + c);   // uniform -> broadcast
      a0 = fmaf(k4.x, qp[-c],     a0);
      a1 = fmaf(k4.y, qp[-c - 1], a1);
      a0 = fmaf(k4.z, qp[-c - 2], a0);
      a1 = fmaf(k4.w, qp[-c - 3], a1);
    }
    qn[J] = a0 + a1;
  }
}

__device__ __forceinline__ void conv8(const float* __restrict__ q,
                                      float* __restrict__ qn,
                                      const float* __restrict__ kvs,
                                      int ML, int T,
                                      int LQ, int HQ, int tid, int nthr)
{
  const int Lout = LQ + ML, Hout = HQ + ML + T;
  for (int J = Lout + tid; J <= Hout; J += nthr) {
    const float* qp = q + (J - ML);
    float a0 = 0.f, a1 = 0.f;
#pragma unroll
    for (int c = 0; c < 8; c += 4) {
      float4 k4 = *(const float4*)(kvs + c);   // uniform -> broadcast
      a0 = fmaf(k4.x, qp[-c],     a0);
      a1 = fmaf(k4.y, qp[-c - 1], a1);
      a0 = fmaf(k4.z, qp[-c - 2], a0);
      a1 = fmaf(k4.w, qp[-c - 3], a1);
    }
    qn[J] = a0 + a1;
  }
}

// ---------- all-atom gather with clamp (wide agents / wide wf) --------------
template<int TA, int TB>
__device__ __forceinline__ float gather_part(const float* __restrict__ pb,
                                             float wv, float j)
{
  float a0 = 0.f, a1 = 0.f, a2 = 0.f, a3 = 0.f;
  const float4* pb4 = (const float4*)pb;
  const float base = 25.0f - j;
#pragma unroll
  for (int t4 = TA; t4 < TB; ++t4) {
    float4 p4 = pb4[t4];
#define G1(PX, TT, AC) { \
    float sup = ((float)(TT) * 0.4f - 10.0f) * wv; \
    float c   = fminf(fmaxf(sup, -10.0f), 10.0f); \
    float d   = fmaf(c, 2.5f, base); \
    AC = fmaf(PX, fmaxf(0.f, 1.0f - fabsf(d)), AC); }
    G1(p4.x, 4 * t4 + 0, a0)
    G1(p4.y, 4 * t4 + 1, a1)
    G1(p4.z, 4 * t4 + 2, a2)
    G1(p4.w, 4 * t4 + 3, a3)
#undef G1
  }
  return (a0 + a1) + (a2 + a3);
}

// ---------- typed loads / dot rows ----------
template<int BF>
__device__ __forceinline__ float ldt(const void* p, int i) {
  if (BF) return bf2f(((const u16*)p)[i]);
  return ((const float*)p)[i];
}

template<int BF>
__device__ __forceinline__ float dot128_t(const void* w, int row, const float* s) {
  float acc = 0.f;
  if (BF) {
    const uint4* p = (const uint4*)((const u16*)w + row * 128);
#pragma unroll
    for (int i = 0; i < 16; ++i) {
      uint4 v = p[i];
      int b = i * 8;
      acc = fmaf(bflo(v.x), s[b + 0], acc); acc = fmaf(bfhi(v.x), s[b + 1], acc);
      acc = fmaf(bflo(v.y), s[b + 2], acc); acc = fmaf(bfhi(v.y), s[b + 3], acc);
      acc = fmaf(bflo(v.z), s[b + 4], acc); acc = fmaf(bfhi(v.z), s[b + 5], acc);
      acc = fmaf(bflo(v.w), s[b + 6], acc); acc = fmaf(bfhi(v.w), s[b + 7], acc);
    }
  } else {
    const float4* p = (const float4*)((const float*)w + row * 128);
#pragma unroll
    for (int i = 0; i < 32; ++i) {
      float4 v = p[i];
      int b = i * 4;
      acc = fmaf(v.x, s[b + 0], acc); acc = fmaf(v.y, s[b + 1], acc);
      acc = fmaf(v.z, s[b + 2], acc); acc = fmaf(v.w, s[b + 3], acc);
    }
  }
  return acc;
}

template<int BF>
__device__ __forceinline__ float dot64_t(const void* w, int row, const float* h) {
  float acc = 0.f;
  if (BF) {
    const uint4* p = (const uint4*)((const u16*)w + row * 64);
#pragma unroll
    for (int i = 0; i < 8; ++i) {
      uint4 v = p[i];
      int b = i * 8;
      acc = fmaf(bflo(v.x), h[b + 0], acc); acc = fmaf(bfhi(v.x), h[b + 1], acc);
      acc = fmaf(bflo(v.y), h[b + 2], acc); acc = fmaf(bfhi(v.y), h[b + 3], acc);
      acc = fmaf(bflo(v.z), h[b + 4], acc); acc = fmaf(bfhi(v.z), h[b + 5], acc);
      acc = fmaf(bflo(v.w), h[b + 6], acc); acc = fmaf(bfhi(v.w), h[b + 7], acc);
    }
  } else {
    const float4* p = (const float4*)((const float*)w + row * 64);
#pragma unroll
    for (int i = 0; i < 16; ++i) {
      float4 v = p[i];
      int b = i * 4;
      acc = fmaf(v.x, h[b + 0], acc); acc = fmaf(v.y, h[b + 1], acc);
      acc = fmaf(v.z, h[b + 2], acc); acc = fmaf(v.w, h[b + 3], acc);
    }
  }
  return acc;
}

// =================== Kernel 1: hypernet MLPs, parallel-row layout ===========
template<int BF>
__device__ __forceinline__ void mlp_par(
    const void* states,
    const void* hw1_w1, const void* hw1_b1, const void* hw1_w2, const void* hw1_b2,
    const void* hb1_w,  const void* hb1_b,
    const void* hwf_w1, const void* hwf_b1, const void* hwf_w2, const void* hwf_b2,
    const void* v_w1,   const void* v_b1,   const void* v_w2,   const void* v_b2,
    float* w1_ws, float* b1_ws, float* wf_ws, float* v_ws,
    float* s_st, float* h1, float* hf, float* vh, int n, int tid)
{
  if (tid < 128) s_st[tid] = ldt<BF>(states, n * 128 + tid);
  __syncthreads();
  if (tid < 64)
    h1[tid] = fmaxf(dot128_t<BF>(hw1_w1, tid, s_st) + ldt<BF>(hw1_b1, tid), 0.f);
  else if (tid < 128)
    hf[tid - 64] = fmaxf(dot128_t<BF>(hwf_w1, tid - 64, s_st) + ldt<BF>(hwf_b1, tid - 64), 0.f);
  else if (tid < 160)
    vh[tid - 128] = fmaxf(dot128_t<BF>(v_w1, tid - 128, s_st) + ldt<BF>(v_b1, tid - 128), 0.f);
  else if (tid < 192)
    b1_ws[n * 32 + tid - 160] = dot128_t<BF>(hb1_w, tid - 160, s_st) + ldt<BF>(hb1_b, tid - 160);
  __syncthreads();
  if (tid < 256)
    w1_ws[n * 256 + tid] = fabsf(dot64_t<BF>(hw1_w2, tid, h1) + ldt<BF>(hw1_b2, tid));
  else if (tid < 288)
    wf_ws[n * 32 + tid - 256] = fabsf(dot64_t<BF>(hwf_w2, tid - 256, hf) + ldt<BF>(hwf_b2, tid - 256));
  else {
    int l2 = tid - 288;                      // wave 4, lanes 32..63
    float part = vh[l2] * ldt<BF>(v_w2, l2);
    part += __shfl_xor(part, 1);  part += __shfl_xor(part, 2);
    part += __shfl_xor(part, 4);  part += __shfl_xor(part, 8);
    part += __shfl_xor(part, 16);
    if (l2 == 0) v_ws[n] = part + ldt<BF>(v_b2, 0);
  }
}

__global__ __launch_bounds__(320) void k_mlp(
    const void* __restrict__ states,
    const void* __restrict__ hw1_w1, const void* __restrict__ hw1_b1,
    const void* __restrict__ hw1_w2, const void* __restrict__ hw1_b2,
    const void* __restrict__ hb1_w,  const void* __restrict__ hb1_b,
    const void* __restrict__ hwf_w1, const void* __restrict__ hwf_b1,
    const void* __restrict__ hwf_w2, const void* __restrict__ hwf_b2,
    const void* __restrict__ v_w1,   const void* __restrict__ v_b1,
    const void* __restrict__ v_w2,   const void* __restrict__ v_b2,
    float* __restrict__ w1_ws, float* __restrict__ b1_ws,
    float* __restrict__ wf_ws, float* __restrict__ v_ws,
    int* __restrict__ flag)
{
  __shared__ float s_st[128];
  __shared__ float h1[64], hf[64], vh[32];
  __shared__ int sh_flag;
  const int n = blockIdx.x;
  const int tid = threadIdx.x;

  // inline dtype detect (wave 0): first 128 u16 words of states (~N(0,1))
  if (tid < 64) {
    const u16* sr = (const u16*)states;
    unsigned int e0 = (sr[tid] >> 7) & 0xFF;
    unsigned int e1 = (sr[tid + 64] >> 7) & 0xFF;
    unsigned long long bl0 = __ballot(e0 >= 97 && e0 <= 141);
    unsigned long long bl1 = __ballot(e1 >= 97 && e1 <= 141);
    int bfv = (__popcll(bl0) + __popcll(bl1) >= 104) ? 1 : 0;
    if (tid == 0) { sh_flag = bfv; *flag = bfv; }   // all blocks same (benign)
  }
  __syncthreads();
  const int bf = sh_flag;

  if (bf)
    mlp_par<1>(states, hw1_w1, hw1_b1, hw1_w2, hw1_b2, hb1_w, hb1_b,
               hwf_w1, hwf_b1, hwf_w2, hwf_b2, v_w1, v_b1, v_w2, v_b2,
               w1_ws, b1_ws, wf_ws, v_ws, s_st, h1, hf, vh, n, tid);
  else
    mlp_par<0>(states, hw1_w1, hw1_b1, hw1_w2, hw1_b2, hb1_w, hb1_b,
               hwf_w1, hwf_b1, hwf_w2, hwf_b2, v_w1, v_b1, v_w2, v_b2,
               w1_ws, b1_ws, wf_ws, v_ws, s_st, h1, hf, vh, n, tid);
}

// ======= Kernel 2: 2 tasks per 128-thread block, one wave per task.
// (Measured-best structure: 126 us, Round 4.)
__global__ __launch_bounds__(128) void k_perembed(
    const void* __restrict__ aq,          // (1024, 8, 51)
    const float* __restrict__ w1_ws, const float* __restrict__ b1_ws,
    const float* __restrict__ wf_ws, float* __restrict__ xw_ws,
    const int* __restrict__ flag)
{
  __shared__ __align__(16) float P[8 * 52];     // probs (both tasks same n)
  __shared__ __align__(16) float TS[2][1332];   // per-task scratch
  // TS[w] layout: Ab 0..519 | Bb 520..1039 | kv 1040..1167 (8x16) |
  //               kvo 1168..1223 | x2 1224..1275 | g 1276..1328 (53)

  const int tid  = threadIdx.x;
  const int w    = tid >> 6;
  const int lane = tid & 63;
  const int task = blockIdx.x * 2 + w;
  const int n = task >> 5;
  const int e = task & 31;
  const int bf = *flag;

  // ---- stage probs (wave w loads rows 4w..4w+3; pad col 51 = 0) ----
  if (bf) {
    const u16* p = (const u16*)aq + n * 408;
    if (lane < 52) {
#pragma unroll
      for (int k = 0; k < 4; ++k) {
        int a = 4 * w + k;
        P[a * 52 + lane] = (lane < 51) ? bf2f(p[a * 51 + lane]) : 0.f;
      }
    }
  } else {
    const float* p = (const float*)aq + n * 408;
    if (lane < 52) {
#pragma unroll
      for (int k = 0; k < 4; ++k) {
        int a = 4 * w + k;
        P[a * 52 + lane] = (lane < 51) ? p[a * 51 + lane] : 0.f;
      }
    }
  }
  float wreg = (lane < 8) ? w1_ws[n * 256 + e * 8 + lane] : 0.f;
  float b1v  = b1_ws[n * 32 + e];
  float wfv  = wf_ws[n * 32 + e];

  int mlA = 0, mhA = 0;
  if (lane < 8) proj_bounds(wreg, mlA, mhA);
  __syncthreads();                       // ONE block barrier: P visible

  float* Ab  = TS[w];
  float* Bb  = Ab + 520;
  float* kv  = Ab + 1040;
  float* kvo = Ab + 1168;
  float* x2  = Ab + 1224;
  float* g   = Ab + 1276;

  // ---- narrow gathers: 2 rounds x (4 agents x 16 bins); T<=15 => no clamp --
#pragma unroll
  for (int r = 0; r < 2; ++r) {
    int a  = 4 * r + (lane >> 4);
    int jj = lane & 15;
    float wv = __shfl(wreg, a);
    int ML = __shfl(mlA, a);
    int MH = __shfl(mhA, a);
    int T  = MH - ML;
    float K = (25.0f - (float)(ML + jj)) - 25.0f * wv;
    float a0 = 0.f, a1 = 0.f, a2 = 0.f, a3 = 0.f;
    const float4* pb4 = (const float4*)(P + a * 52);
#pragma unroll
    for (int t4 = 0; t4 < 13; ++t4) {
      float4 p4 = pb4[t4];               // wave-uniform per 16-lane group
      float d0 = fmaf((float)(4 * t4 + 0), wv, K);
      float d1 = fmaf((float)(4 * t4 + 1), wv, K);
      float d2 = fmaf((float)(4 * t4 + 2), wv, K);
      float d3 = fmaf((float)(4 * t4 + 3), wv, K);
      a0 = fmaf(p4.x, fmaxf(0.f, 1.0f - fabsf(d0)), a0);
      a1 = fmaf(p4.y, fmaxf(0.f, 1.0f - fabsf(d1)), a1);
      a2 = fmaf(p4.z, fmaxf(0.f, 1.0f - fabsf(d2)), a2);
      a3 = fmaf(p4.w, fmaxf(0.f, 1.0f - fabsf(d3)), a3);
    }
    if (T <= 15)
      kv[a * 16 + jj] = (jj <= T) ? ((a0 + a1) + (a2 + a3)) : 0.f;
  }
  WAVE_SYNC();

  // ---- seed: agent 0 ----
  int LQ, HQ;
  float* q = Ab;
  float* qn = Bb;
  {
    float wv0 = __shfl(wreg, 0);
    int ML0 = __shfl(mlA, 0), MH0 = __shfl(mhA, 0);
    int T0 = MH0 - ML0;
    if (T0 <= 15) {
      if (lane <= T0) Ab[64 + ML0 + lane] = kv[lane];
    } else {
      float acc = gather_part<0, 13>(P, wv0, (float)(ML0 + lane));
      if (lane <= T0) Ab[64 + ML0 + lane] = acc;
    }
    WAVE_SYNC();
    LQ = 64 + ML0; HQ = 64 + MH0;
  }

  // ---- conv chain over agents 1..7 ----
  for (int a = 1; a < 8; ++a) {
    float wv = __shfl(wreg, a);
    int ML = __shfl(mlA, a), MH = __shfl(mhA, a);
    int T = MH - ML;
    const float* kvs;
    int W;
    if (T <= 15) {                       // wave-uniform branch
      kvs = kv + a * 16;
      W = (T <= 7) ? 8 : 16;
    } else {                             // rare wide agent
      float acc = gather_part<0, 13>(P + a * 52, wv, (float)(ML + lane));
      W = (T + 4) & ~3;                  // <= 52
      if (lane < W) kvo[lane] = (lane <= T) ? acc : 0.f;
      kvs = kvo;
    }
    if (lane < W - 1) q[LQ - 1 - lane] = 0.f;
    if (lane < T)     q[HQ + 1 + lane] = 0.f;
    WAVE_SYNC();
    if (T <= 7)       conv8 (q, qn, kvs, ML, T, LQ, HQ, lane, 64);
    else if (T <= 15) conv16(q, qn, kvs, ML, T, LQ, HQ, lane, 64);
    else              conv_pad2(q, qn, kvs, ML, W, T, LQ, HQ, lane, 64);
    WAVE_SYNC();
    LQ += ML; HQ += MH;
    float* t_ = q; q = qn; qn = t_;
  }

  // ---- elu projection via LDS atomicAdd (wave-local buffer) ----
  {
    if (lane < 53) g[lane] = 0.f;
    WAVE_SYNC();
    int span = HQ - LQ + 1;
    for (int base = 0; base < span; base += 64) {
      int t = base + lane;
      if (t < span) {
        int tg = (LQ - 64) + t;          // grid index in [0,400]
        float raw = (-80.0f + 0.4f * (float)tg) + b1v;
        float sup = (raw > 0.f) ? raw : expm1f(raw);
        float c  = fminf(fmaxf(sup, -10.0f), 10.0f);
        float b  = (c + 10.0f) / 0.4f;
        float l  = floorf(b);
        float u  = ceilf(b);
        float eq = (u == l) ? 1.0f : 0.0f;
        float p  = q[LQ + t];
        int   li = (int)l;
        atomicAdd(&g[li],     p * (u - b + eq));
        atomicAdd(&g[li + 1], p * (b - l));
      }
    }
    WAVE_SYNC();
  }
  if (lane < 52) x2[lane] = (lane < 51) ? g[lane] : 0.f;
  WAVE_SYNC();

  // ---- wf projection -> xw row ----
  {
    int MLf, MHf;
    proj_bounds(wfv, MLf, MHf);          // uniform across wave
    int Tf = MHf - MLf;
    if (Tf <= 15) {
      // strided split: lane = q4*16+jj gathers atoms t = q4+4k (no clamp:
      // wv<=~0.3 -> |sup|<=3); combine the 4 quarters with 2 shfl_xor.
      int q4 = lane >> 4, jj = lane & 15;
      float K = (25.0f - (float)(MLf + jj)) - 25.0f * wfv;
      float acc = 0.f;
#pragma unroll
      for (int k = 0; k < 13; ++k) {
        int t = q4 + 4 * k;
        float d = fmaf((float)t, wfv, K);
        acc = fmaf(x2[t], fmaxf(0.f, 1.0f - fabsf(d)), acc);
      }
      acc += __shfl_xor(acc, 16);
      acc += __shfl_xor(acc, 32);
      if (lane <= Tf)                    // Tf<=15 -> lanes 0..15, jj==lane
        xw_ws[task * 51 + MLf + lane] = acc;
    } else {
      float acc = gather_part<0, 13>(x2, wfv, (float)(MLf + lane));
      if (lane <= Tf)
        xw_ws[task * 51 + MLf + lane] = acc;
    }
  }
}

// ====== Kernel 3: TREE convolution — depth 5, 512 threads, R=4 register-
// blocked conv: each thread computes 4 consecutive outputs with a 7-value
// sliding q-window in VGPRs. 4 new q-reads per 16 MACs (~1 B/MAC of LDS
// traffic vs ~2.5 before) — attacks the LDS-BW bound. Guard zones: reads
// extend to row+/-(W+3); inter-row gaps >= G=(lm+11)&~3 >= lB+8, zeroed.
__global__ __launch_bounds__(512) void k_final(
    const float* __restrict__ xw_ws, const float* __restrict__ wf_ws,
    const float* __restrict__ v_ws,
    void* __restrict__ out, const int* __restrict__ flag)
{
  __shared__ __align__(16) float bufA[4608];
  __shared__ __align__(16) float bufB[4608];
  __shared__ int meta_s[63];
  __shared__ int meta_l[63];
  __shared__ int meta_ml[32];
  __shared__ int meta_g[6];
  __shared__ int meta_mltot;
  __shared__ float gA[53];

  const int n    = blockIdx.x;
  const int tid  = threadIdx.x;
  const int lane = tid & 63;
  const int bf   = *flag;

  float vv = v_ws[n];

  for (int i = tid; i < 4608; i += 512) { bufA[i] = 0.f; bufB[i] = 0.f; }
  if (tid < 53) gA[tid] = 0.f;

  if (tid < 64) {
    float wfreg = (lane < 32) ? wf_ws[n * 32 + lane] : 0.f;
    int ml, mh;
    proj_bounds(wfreg, ml, mh);
    if (lane < 32) meta_ml[lane] = ml;
    int msum = ml;
#pragma unroll
    for (int d = 1; d < 32; d <<= 1) msum += __shfl_xor(msum, d);
    if (lane == 0) meta_mltot = msum;

    int curlen = mh - ml + 1;
    int base = 0, Ncur = 32;
#pragma unroll
    for (int c = 0; c <= 5; ++c) {
      int lm = (lane < Ncur) ? curlen : 0;
#pragma unroll
      for (int d = 1; d < 32; d <<= 1) {
        int o = __shfl_xor(lm, d);
        lm = (o > lm) ? o : lm;
      }
      int G = (lm + 11) & ~3;
      int sp = ((curlen + 3) & ~3) + G;
      int inc = (lane < Ncur) ? sp : 0;
      int v0 = inc;
#pragma unroll
      for (int d = 1; d < 32; d <<= 1) {
        int u = __shfl_up(inc, d);
        if (lane >= d && lane < 32) inc += u;
      }
      if (lane < Ncur) {
        meta_s[base + lane] = 832 + (inc - v0);
        meta_l[base + lane] = curlen;
      }
      if (lane == 0) meta_g[c] = G;
      if (c < 5) {
        int l0 = __shfl(curlen, 2 * lane);
        int l1 = __shfl(curlen, 2 * lane + 1);
        curlen = l0 + l1 - 1;
        base += Ncur;
        Ncur >>= 1;
      }
    }
  }
  __syncthreads();

  {
    int g = tid >> 4, i3 = tid & 15;     // 16 threads per embed row
    int s2 = meta_s[g], l2 = meta_l[g], ml = meta_ml[g];
    const float* row = xw_ws + (n * 32 + g) * 51 + ml;
    for (int i0 = i3; i0 < l2; i0 += 16) bufA[s2 + i0] = row[i0];
  }
  __syncthreads();

#pragma unroll
  for (int c = 1; c <= 5; ++c) {
    const float* bin = (c & 1) ? bufA : bufB;
    float*       bout = (c & 1) ? bufB : bufA;
    const int Nout = 32 >> c;
    const int lg = 4 + c;                // 512-thread split: gs*Nout == 512
    const int gs = 1 << lg;
    const int k  = tid >> lg;
    const int st = tid & (gs - 1);
    const int bc = 64 - (64 >> c);
    const int bp = 64 - (64 >> (c - 1));
    const int i0 = bp + 2 * k;
    const int sA = meta_s[i0];
    const int sB = meta_s[i0 + 1];
    const int lB = meta_l[i0 + 1];
    const int sO = meta_s[bc + k];
    const int lO = meta_l[bc + k];
    const int W  = (lB + 3) & ~3;
    const int W4 = W >> 2;

    // out[j+r] = sum_c k[c] * A[sA + j + r - c]; R=4 outputs per thread,
    // sliding 7-value q-window, 4 new reads per 4-tap group.
    for (int j = st * 4; j < lO; j += gs * 4) {
      const float* Abase = bin + sA + j;
      float a0 = 0.f, a1 = 0.f, a2 = 0.f, a3 = 0.f;
      float q0 = Abase[3],  q1 = Abase[2],  q2 = Abase[1],  q3 = Abase[0],
            q4 = Abase[-1], q5 = Abase[-2], q6 = Abase[-3];
      const float4* kb = (const float4*)(bin + sB);
      for (int g = 0; g < W4; ++g) {
        float4 k4 = kb[g];               // uniform -> broadcast
        a0 = fmaf(k4.x, q3, a0); a1 = fmaf(k4.x, q2, a1);
        a2 = fmaf(k4.x, q1, a2); a3 = fmaf(k4.x, q0, a3);
        a0 = fmaf(k4.y, q4, a0); a1 = fmaf(k4.y, q3, a1);
        a2 = fmaf(k4.y, q2, a2); a3 = fmaf(k4.y, q1, a3);
        a0 = fmaf(k4.z, q5, a0); a1 = fmaf(k4.z, q4, a1);
        a2 = fmaf(k4.z, q3, a2); a3 = fmaf(k4.z, q2, a3);
        a0 = fmaf(k4.w, q6, a0); a1 = fmaf(k4.w, q5, a1);
        a2 = fmaf(k4.w, q4, a2); a3 = fmaf(k4.w, q3, a3);
        q0 = q4; q1 = q5; q2 = q6;
        int b2 = -4 - 4 * g;
        q3 = Abase[b2];     q4 = Abase[b2 - 1];
        q5 = Abase[b2 - 2]; q6 = Abase[b2 - 3];
      }
      bout[sO + j] = a0;
      if (j + 1 < lO) bout[sO + j + 1] = a1;
      if (j + 2 < lO) bout[sO + j + 2] = a2;
      if (j + 3 < lO) bout[sO + j + 3] = a3;
    }

    if (c >= 2 && c <= 4) {
      int G = meta_g[c];
      for (int p = tid; p < G; p += 512) bout[832 - G + p] = 0.f;
      for (int k2 = 0; k2 < Nout; ++k2) {
        int ss = meta_s[bc + k2] + meta_l[bc + k2];
        int ee = (k2 + 1 < Nout) ? meta_s[bc + k2 + 1]
                                 : ss + G + 3;
        for (int p = ss + tid; p < ee; p += 512) bout[p] = 0.f;
      }
    }
    __syncthreads();
  }

  // ---- final projection via LDS atomicAdd across all 512 threads ----
  {
    int s5 = meta_s[62], l5 = meta_l[62], mlt = meta_mltot;
    const float* qf = bufB + s5;
    for (int t = tid; t < l5; t += 512) {
      int tg = mlt + t;
      float sup = (-320.0f + 0.4f * (float)tg) + vv;
      float c  = fminf(fmaxf(sup, -10.0f), 10.0f);
      float b  = (c + 10.0f) / 0.4f;
      float l  = floorf(b);
      float u  = ceilf(b);
      float eq = (u == l) ? 1.0f : 0.0f;
      float p  = qf[t];
      int   li = (int)l;
      atomicAdd(&gA[li],     p * (u - b + eq));
      atomicAdd(&gA[li + 1], p * (b - l));
    }
  }
  __syncthreads();
  if (tid < 51) {
    float o = gA[tid];
    if (bf) ((u16*)out)[n * 51 + tid] = f2bf(o);
    else    ((float*)out)[n * 51 + tid] = o;
  }
}

// =========================== launcher ===========================
extern "C" void kernel_launch(void* const* d_in, const int* in_sizes, int n_in,
                              void* d_out, int out_size, void* d_ws, size_t ws_size,
                              hipStream_t stream)
{
  float* ws    = (float*)d_ws;
  float* w1_ws = ws;                       // 1024*256
  float* b1_ws = w1_ws + 1024 * 256;       // 1024*32
  float* wf_ws = b1_ws + 1024 * 32;        // 1024*32
  float* v_ws  = wf_ws + 1024 * 32;        // 1024
  float* xw_ws = v_ws  + 1024;             // 1024*32*51
  int*   flag  = (int*)(xw_ws + 1024 * 32 * 51);

  k_mlp<<<1024, 320, 0, stream>>>(d_in[1],
      d_in[2], d_in[3], d_in[4], d_in[5], d_in[6], d_in[7],
      d_in[8], d_in[9], d_in[10], d_in[11], d_in[12], d_in[13],
      d_in[14], d_in[15],
      w1_ws, b1_ws, wf_ws, v_ws, flag);

  k_perembed<<<16384, 128, 0, stream>>>(d_in[0], w1_ws, b1_ws, wf_ws, xw_ws, flag);

  k_final<<<1024, 512, 0, stream>>>(xw_ws, wf_ws, v_ws, d_out, flag);
}

// Round 7
// 251.158 us; speedup vs baseline: 1.3301x; 1.0018x over previous
//
#include <hip/hip_runtime.h>
#include <hip/hip_bf16.h>
#include <math.h>

typedef unsigned short u16;

// Wave-local LDS drain (same-wave DS ops execute in order; this also fences
// the compiler).
#define WAVE_SYNC() asm volatile("s_waitcnt lgkmcnt(0)" ::: "memory")

// ---------- dtype helpers ----------
__device__ __forceinline__ float bf2f(u16 u) {
  union { unsigned int i; float f; } c;
  c.i = ((unsigned int)u) << 16;
  return c.f;
}
__device__ __forceinline__ float bflo(unsigned int u) {
  union { unsigned int i; float f; } c; c.i = u << 16; return c.f;
}
__device__ __forceinline__ float bfhi(unsigned int u) {
  union { unsigned int i; float f; } c; c.i = u & 0xffff0000u; return c.f;
}
__device__ __forceinline__ u16 f2bf(float f) {
  union { float f; unsigned int i; } c;
  c.f = f;
  unsigned int x = c.i;
  unsigned int r = (x + 0x7fffu + ((x >> 16) & 1u)) >> 16; // RNE
  return (u16)r;
}

// Destination-bin bounds for proj of supports (-10+0.4t)*wv, t=0..50, wv>=0.
__device__ __forceinline__ void proj_bounds(float wv, int& ML, int& MH) {
  float smin = (-10.0f + 0.4f * 0.0f)  * wv;
  float smax = (-10.0f + 0.4f * 50.0f) * wv;
  float bmin = (fminf(fmaxf(smin, -10.0f), 10.0f) + 10.0f) / 0.4f;
  float bmax = (fminf(fmaxf(smax, -10.0f), 10.0f) + 10.0f) / 0.4f;
  ML = (int)floorf(bmin);
  MH = (int)ceilf(bmax);
}

// ---------- runtime-width convolution (wide agents only), output-capped ----
__device__ __forceinline__ void conv_pad2(const float* __restrict__ q,
                                          float* __restrict__ qn,
                                          const float* __restrict__ kvs,
                                          int ML, int W, int T,
                                          int LQ, int HQ, int Jmax,
                                          int tid, int nthr)
{
  const int Lout = LQ + ML;
  const int Hout = min(HQ + ML + T, Jmax);
  for (int J = Lout + tid; J <= Hout; J += nthr) {
    const float* qp = q + (J - ML);
    float acc = 0.f;
    for (int c = 0; c < W; c += 4) {
      float4 k4 = *(const float4*)(kvs + c);   // uniform address -> broadcast
      acc = fmaf(k4.x, qp[-c],     acc);
      acc = fmaf(k4.y, qp[-c - 1], acc);
      acc = fmaf(k4.z, qp[-c - 2], acc);
      acc = fmaf(k4.w, qp[-c - 3], acc);
    }
    qn[J] = acc;
  }
}

// ---------- fixed-tap fully-unrolled convolutions (narrow agents) -----------
__device__ __forceinline__ void conv16(const float* __restrict__ q,
                                       float* __restrict__ qn,
                                       const float* __restrict__ kvs,
                                       int ML, int T,
                                       int LQ, int HQ, int Jmax,
                                       int tid, int nthr)
{
  const int Lout = LQ + ML;
  const int Hout = min(HQ + ML + T, Jmax);
  for (int J = Lout + tid; J <= Hout; J += nthr) {
    const float* qp = q + (J - ML);
    float a0 = 0.f, a1 = 0.f;
#pragma unroll
    for (int c = 0; c < 16; c += 4) {
      float4 k4 = *(const float4*)(kvs + c);   // uniform -> broadcast
      a0 = fmaf(k4.x, qp[-c],     a0);
      a1 = fmaf(k4.y, qp[-c - 1], a1);
      a0 = fmaf(k4.z, qp[-c - 2], a0);
      a1 = fmaf(k4.w, qp[-c - 3], a1);
    }
    qn[J] = a0 + a1;
  }
}

__device__ __forceinline__ void conv8(const float* __restrict__ q,
                                      float* __restrict__ qn,
                                      const float* __restrict__ kvs,
                                      int ML, int T,
                                      int LQ, int HQ, int Jmax,
                                      int tid, int nthr)
{
  const int Lout = LQ + ML;
  const int Hout = min(HQ + ML + T, Jmax);
  for (int J = Lout + tid; J <= Hout; J += nthr) {
    const float* qp = q + (J - ML);
    float a0 = 0.f, a1 = 0.f;
#pragma unroll
    for (int c = 0; c < 8; c += 4) {
      float4 k4 = *(const float4*)(kvs + c);   // uniform -> broadcast
      a0 = fmaf(k4.x, qp[-c],     a0);
      a1 = fmaf(k4.y, qp[-c - 1], a1);
      a0 = fmaf(k4.z, qp[-c - 2], a0);
      a1 = fmaf(k4.w, qp[-c - 3], a1);
    }
    qn[J] = a0 + a1;
  }
}

// ---------- all-atom gather with clamp (wide agents / wide wf) --------------
template<int TA, int TB>
__device__ __forceinline__ float gather_part(const float* __restrict__ pb,
                                             float wv, float j)
{
  float a0 = 0.f, a1 = 0.f, a2 = 0.f, a3 = 0.f;
  const float4* pb4 = (const float4*)pb;
  const float base = 25.0f - j;
#pragma unroll
  for (int t4 = TA; t4 < TB; ++t4) {
    float4 p4 = pb4[t4];
#define G1(PX, TT, AC) { \
    float sup = ((float)(TT) * 0.4f - 10.0f) * wv; \
    float c   = fminf(fmaxf(sup, -10.0f), 10.0f); \
    float d   = fmaf(c, 2.5f, base); \
    AC = fmaf(PX, fmaxf(0.f, 1.0f - fabsf(d)), AC); }
    G1(p4.x, 4 * t4 + 0, a0)
    G1(p4.y, 4 * t4 + 1, a1)
    G1(p4.z, 4 * t4 + 2, a2)
    G1(p4.w, 4 * t4 + 3, a3)
#undef G1
  }
  return (a0 + a1) + (a2 + a3);
}

// ---------- typed loads / dot rows ----------
template<int BF>
__device__ __forceinline__ float ldt(const void* p, int i) {
  if (BF) return bf2f(((const u16*)p)[i]);
  return ((const float*)p)[i];
}

template<int BF>
__device__ __forceinline__ float dot128_t(const void* w, int row, const float* s) {
  float acc = 0.f;
  if (BF) {
    const uint4* p = (const uint4*)((const u16*)w + row * 128);
#pragma unroll
    for (int i = 0; i < 16; ++i) {
      uint4 v = p[i];
      int b = i * 8;
      acc = fmaf(bflo(v.x), s[b + 0], acc); acc = fmaf(bfhi(v.x), s[b + 1], acc);
      acc = fmaf(bflo(v.y), s[b + 2], acc); acc = fmaf(bfhi(v.y), s[b + 3], acc);
      acc = fmaf(bflo(v.z), s[b + 4], acc); acc = fmaf(bfhi(v.z), s[b + 5], acc);
      acc = fmaf(bflo(v.w), s[b + 6], acc); acc = fmaf(bfhi(v.w), s[b + 7], acc);
    }
  } else {
    const float4* p = (const float4*)((const float*)w + row * 128);
#pragma unroll
    for (int i = 0; i < 32; ++i) {
      float4 v = p[i];
      int b = i * 4;
      acc = fmaf(v.x, s[b + 0], acc); acc = fmaf(v.y, s[b + 1], acc);
      acc = fmaf(v.z, s[b + 2], acc); acc = fmaf(v.w, s[b + 3], acc);
    }
  }
  return acc;
}

template<int BF>
__device__ __forceinline__ float dot64_t(const void* w, int row, const float* h) {
  float acc = 0.f;
  if (BF) {
    const uint4* p = (const uint4*)((const u16*)w + row * 64);
#pragma unroll
    for (int i = 0; i < 8; ++i) {
      uint4 v = p[i];
      int b = i * 8;
      acc = fmaf(bflo(v.x), h[b + 0], acc); acc = fmaf(bfhi(v.x), h[b + 1], acc);
      acc = fmaf(bflo(v.y), h[b + 2], acc); acc = fmaf(bfhi(v.y), h[b + 3], acc);
      acc = fmaf(bflo(v.z), h[b + 4], acc); acc = fmaf(bfhi(v.z), h[b + 5], acc);
      acc = fmaf(bflo(v.w), h[b + 6], acc); acc = fmaf(bfhi(v.w), h[b + 7], acc);
    }
  } else {
    const float4* p = (const float4*)((const float*)w + row * 64);
#pragma unroll
    for (int i = 0; i < 16; ++i) {
      float4 v = p[i];
      int b = i * 4;
      acc = fmaf(v.x, h[b + 0], acc); acc = fmaf(v.y, h[b + 1], acc);
      acc = fmaf(v.z, h[b + 2], acc); acc = fmaf(v.w, h[b + 3], acc);
    }
  }
  return acc;
}

// =================== Kernel 1: hypernet MLPs, parallel-row layout ===========
template<int BF>
__device__ __forceinline__ void mlp_par(
    const void* states,
    const void* hw1_w1, const void* hw1_b1, const void* hw1_w2, const void* hw1_b2,
    const void* hb1_w,  const void* hb1_b,
    const void* hwf_w1, const void* hwf_b1, const void* hwf_w2, const void* hwf_b2,
    const void* v_w1,   const void* v_b1,   const void* v_w2,   const void* v_b2,
    float* w1_ws, float* b1_ws, float* wf_ws, float* v_ws,
    float* s_st, float* h1, float* hf, float* vh, int n, int tid)
{
  if (tid < 128) s_st[tid] = ldt<BF>(states, n * 128 + tid);
  __syncthreads();
  if (tid < 64)
    h1[tid] = fmaxf(dot128_t<BF>(hw1_w1, tid, s_st) + ldt<BF>(hw1_b1, tid), 0.f);
  else if (tid < 128)
    hf[tid - 64] = fmaxf(dot128_t<BF>(hwf_w1, tid - 64, s_st) + ldt<BF>(hwf_b1, tid - 64), 0.f);
  else if (tid < 160)
    vh[tid - 128] = fmaxf(dot128_t<BF>(v_w1, tid - 128, s_st) + ldt<BF>(v_b1, tid - 128), 0.f);
  else if (tid < 192)
    b1_ws[n * 32 + tid - 160] = dot128_t<BF>(hb1_w, tid - 160, s_st) + ldt<BF>(hb1_b, tid - 160);
  __syncthreads();
  if (tid < 256)
    w1_ws[n * 256 + tid] = fabsf(dot64_t<BF>(hw1_w2, tid, h1) + ldt<BF>(hw1_b2, tid));
  else if (tid < 288)
    wf_ws[n * 32 + tid - 256] = fabsf(dot64_t<BF>(hwf_w2, tid - 256, hf) + ldt<BF>(hwf_b2, tid - 256));
  else {
    int l2 = tid - 288;                      // wave 4, lanes 32..63
    float part = vh[l2] * ldt<BF>(v_w2, l2);
    part += __shfl_xor(part, 1);  part += __shfl_xor(part, 2);
    part += __shfl_xor(part, 4);  part += __shfl_xor(part, 8);
    part += __shfl_xor(part, 16);
    if (l2 == 0) v_ws[n] = part + ldt<BF>(v_b2, 0);
  }
}

__global__ __launch_bounds__(320) void k_mlp(
    const void* __restrict__ states,
    const void* __restrict__ hw1_w1, const void* __restrict__ hw1_b1,
    const void* __restrict__ hw1_w2, const void* __restrict__ hw1_b2,
    const void* __restrict__ hb1_w,  const void* __restrict__ hb1_b,
    const void* __restrict__ hwf_w1, const void* __restrict__ hwf_b1,
    const void* __restrict__ hwf_w2, const void* __restrict__ hwf_b2,
    const void* __restrict__ v_w1,   const void* __restrict__ v_b1,
    const void* __restrict__ v_w2,   const void* __restrict__ v_b2,
    float* __restrict__ w1_ws, float* __restrict__ b1_ws,
    float* __restrict__ wf_ws, float* __restrict__ v_ws,
    int* __restrict__ flag)
{
  __shared__ float s_st[128];
  __shared__ float h1[64], hf[64], vh[32];
  __shared__ int sh_flag;
  const int n = blockIdx.x;
  const int tid = threadIdx.x;

  // inline dtype detect (wave 0): first 128 u16 words of states (~N(0,1))
  if (tid < 64) {
    const u16* sr = (const u16*)states;
    unsigned int e0 = (sr[tid] >> 7) & 0xFF;
    unsigned int e1 = (sr[tid + 64] >> 7) & 0xFF;
    unsigned long long bl0 = __ballot(e0 >= 97 && e0 <= 141);
    unsigned long long bl1 = __ballot(e1 >= 97 && e1 <= 141);
    int bfv = (__popcll(bl0) + __popcll(bl1) >= 104) ? 1 : 0;
    if (tid == 0) { sh_flag = bfv; *flag = bfv; }   // all blocks same (benign)
  }
  __syncthreads();
  const int bf = sh_flag;

  if (bf)
    mlp_par<1>(states, hw1_w1, hw1_b1, hw1_w2, hw1_b2, hb1_w, hb1_b,
               hwf_w1, hwf_b1, hwf_w2, hwf_b2, v_w1, v_b1, v_w2, v_b2,
               w1_ws, b1_ws, wf_ws, v_ws, s_st, h1, hf, vh, n, tid);
  else
    mlp_par<0>(states, hw1_w1, hw1_b1, hw1_w2, hw1_b2, hb1_w, hb1_b,
               hwf_w1, hwf_b1, hwf_w2, hwf_b2, v_w1, v_b1, v_w2, v_b2,
               w1_ws, b1_ws, wf_ws, v_ws, s_st, h1, hf, vh, n, tid);
}

// ======= Kernel 2: 2 tasks per 128-thread block, one wave per task.
// Round-4 proven structure + CLAMP-SUFFIX CAP: atoms of the elu projection
// with raw >= 10 land entirely in bin 50; their total mass equals
// prod_a sum(kv_a) minus the window mass, so the conv chain and the elu
// projection are truncated at grid index tgmax = ceil((90-b1)*2.5).
// Typical effect: chain spans capped ~100 -> ~35 (fewer conv iterations),
// elu 2-3 chunks -> 1 chunk (fewer expm1 + atomics + drains).
__global__ __launch_bounds__(128) void k_perembed(
    const void* __restrict__ aq,          // (1024, 8, 51)
    const float* __restrict__ w1_ws, const float* __restrict__ b1_ws,
    const float* __restrict__ wf_ws, float* __restrict__ xw_ws,
    const int* __restrict__ flag)
{
  __shared__ __align__(16) float P[8 * 52];     // probs (both tasks same n)
  __shared__ __align__(16) float TS[2][1344];   // per-task scratch
  // TS[w] layout: Ab 0..519 | Bb 520..1039 | kv 1040..1167 (8x16) |
  //               kvo 1168..1223 | x2 1224..1275 | g 1276..1328 (53) |
  //               kvsum 1332..1339 (8)

  const int tid  = threadIdx.x;
  const int w    = tid >> 6;
  const int lane = tid & 63;
  const int task = blockIdx.x * 2 + w;
  const int n = task >> 5;
  const int e = task & 31;
  const int bf = *flag;

  // ---- stage probs (wave w loads rows 4w..4w+3; pad col 51 = 0) ----
  if (bf) {
    const u16* p = (const u16*)aq + n * 408;
    if (lane < 52) {
#pragma unroll
      for (int k = 0; k < 4; ++k) {
        int a = 4 * w + k;
        P[a * 52 + lane] = (lane < 51) ? bf2f(p[a * 51 + lane]) : 0.f;
      }
    }
  } else {
    const float* p = (const float*)aq + n * 408;
    if (lane < 52) {
#pragma unroll
      for (int k = 0; k < 4; ++k) {
        int a = 4 * w + k;
        P[a * 52 + lane] = (lane < 51) ? p[a * 51 + lane] : 0.f;
      }
    }
  }
  float wreg = (lane < 8) ? w1_ws[n * 256 + e * 8 + lane] : 0.f;
  float b1v  = b1_ws[n * 32 + e];
  float wfv  = wf_ws[n * 32 + e];

  // cap: grid index where raw = -80 + 0.4*tg + b1 >= 10 (suffix -> bin 50)
  int tgmax = (int)ceilf((90.0f - b1v) * 2.5f);
  if (tgmax < 0) tgmax = 0;
  const int Jcap = 64 + tgmax - 1;       // highest LDS position ever needed

  int mlA = 0, mhA = 0;
  if (lane < 8) proj_bounds(wreg, mlA, mhA);
  __syncthreads();                       // ONE block barrier: P visible

  float* Ab    = TS[w];
  float* Bb    = Ab + 520;
  float* kv    = Ab + 1040;
  float* kvo   = Ab + 1168;
  float* x2    = Ab + 1224;
  float* g     = Ab + 1276;
  float* kvsum = Ab + 1332;

  // ---- narrow gathers: 2 rounds x (4 agents x 16 bins); T<=15 => no clamp --
#pragma unroll
  for (int r = 0; r < 2; ++r) {
    int a  = 4 * r + (lane >> 4);
    int jj = lane & 15;
    float wv = __shfl(wreg, a);
    int ML = __shfl(mlA, a);
    int MH = __shfl(mhA, a);
    int T  = MH - ML;
    float K = (25.0f - (float)(ML + jj)) - 25.0f * wv;
    float a0 = 0.f, a1 = 0.f, a2 = 0.f, a3 = 0.f;
    const float4* pb4 = (const float4*)(P + a * 52);
#pragma unroll
    for (int t4 = 0; t4 < 13; ++t4) {
      float4 p4 = pb4[t4];               // wave-uniform per 16-lane group
      float d0 = fmaf((float)(4 * t4 + 0), wv, K);
      float d1 = fmaf((float)(4 * t4 + 1), wv, K);
      float d2 = fmaf((float)(4 * t4 + 2), wv, K);
      float d3 = fmaf((float)(4 * t4 + 3), wv, K);
      a0 = fmaf(p4.x, fmaxf(0.f, 1.0f - fabsf(d0)), a0);
      a1 = fmaf(p4.y, fmaxf(0.f, 1.0f - fabsf(d1)), a1);
      a2 = fmaf(p4.z, fmaxf(0.f, 1.0f - fabsf(d2)), a2);
      a3 = fmaf(p4.w, fmaxf(0.f, 1.0f - fabsf(d3)), a3);
    }
    float tot = (jj <= T) ? ((a0 + a1) + (a2 + a3)) : 0.f;
    if (T <= 15) {
      kv[a * 16 + jj] = tot;
      float s = tot;                     // per-agent mass (group-16 reduce)
      s += __shfl_xor(s, 1); s += __shfl_xor(s, 2);
      s += __shfl_xor(s, 4); s += __shfl_xor(s, 8);
      if (jj == 0) kvsum[a] = s;
    }
  }
  WAVE_SYNC();

  // ---- seed: agent 0 ----
  int LQ, HQ;
  float* q = Ab;
  float* qn = Bb;
  {
    float wv0 = __shfl(wreg, 0);
    int ML0 = __shfl(mlA, 0), MH0 = __shfl(mhA, 0);
    int T0 = MH0 - ML0;
    if (T0 <= 15) {
      if (lane <= T0 && 64 + ML0 + lane <= Jcap)
        Ab[64 + ML0 + lane] = kv[lane];
    } else {
      float acc = gather_part<0, 13>(P, wv0, (float)(ML0 + lane));
      float s = (lane <= T0) ? acc : 0.f;
#pragma unroll
      for (int d = 1; d < 64; d <<= 1) s += __shfl_xor(s, d);
      if (lane == 0) kvsum[0] = s;
      if (lane <= T0 && 64 + ML0 + lane <= Jcap)
        Ab[64 + ML0 + lane] = acc;
    }
    WAVE_SYNC();
    LQ = 64 + ML0; HQ = 64 + MH0;
  }

  // ---- conv chain over agents 1..7 (outputs capped at Jcap) ----
  for (int a = 1; a < 8; ++a) {
    float wv = __shfl(wreg, a);
    int ML = __shfl(mlA, a), MH = __shfl(mhA, a);
    int T = MH - ML;
    const float* kvs;
    int W;
    if (T <= 15) {                       // wave-uniform branch
      kvs = kv + a * 16;
      W = (T <= 7) ? 8 : 16;
    } else {                             // rare wide agent
      float acc = gather_part<0, 13>(P + a * 52, wv, (float)(ML + lane));
      float s = (lane <= T) ? acc : 0.f;
#pragma unroll
      for (int d = 1; d < 64; d <<= 1) s += __shfl_xor(s, d);
      if (lane == 0) kvsum[a] = s;
      W = (T + 4) & ~3;                  // <= 52
      if (lane < W) kvo[lane] = (lane <= T) ? acc : 0.f;
      kvs = kvo;
    }
    if (lane < W - 1) q[LQ - 1 - lane] = 0.f;
    if (lane < T)     q[HQ + 1 + lane] = 0.f;
    WAVE_SYNC();
    if (T <= 7)       conv8 (q, qn, kvs, ML, T, LQ, HQ, Jcap, lane, 64);
    else if (T <= 15) conv16(q, qn, kvs, ML, T, LQ, HQ, Jcap, lane, 64);
    else              conv_pad2(q, qn, kvs, ML, W, T, LQ, HQ, Jcap, lane, 64);
    WAVE_SYNC();
    LQ += ML; HQ += MH;
    float* t_ = q; q = qn; qn = t_;
  }

  // ---- elu projection via LDS atomicAdd, capped window + suffix mass ----
  {
    if (lane < 53) g[lane] = 0.f;
    WAVE_SYNC();
    int top  = min(HQ, Jcap);
    int span = top - LQ + 1;             // may be <= 0 (all mass in suffix)
    float wsum = 0.f;
    for (int base = 0; base < span; base += 64) {
      int t = base + lane;
      if (t < span) {
        int tg = (LQ - 64) + t;          // grid index in [0,400]
        float raw = (-80.0f + 0.4f * (float)tg) + b1v;
        float sup = (raw > 0.f) ? raw : expm1f(raw);
        float c  = fminf(fmaxf(sup, -10.0f), 10.0f);
        float b  = (c + 10.0f) / 0.4f;
        float l  = floorf(b);
        float u  = ceilf(b);
        float eq = (u == l) ? 1.0f : 0.0f;
        float p  = q[LQ + t];
        int   li = (int)l;
        wsum += p;
        atomicAdd(&g[li],     p * (u - b + eq));
        atomicAdd(&g[li + 1], p * (b - l));
      }
    }
#pragma unroll
    for (int d = 1; d < 64; d <<= 1) wsum += __shfl_xor(wsum, d);
    float tots = kvsum[0];               // total chain mass = prod of sums
#pragma unroll
    for (int a2 = 1; a2 < 8; ++a2) tots *= kvsum[a2];
    WAVE_SYNC();                         // atomics drained
    if (lane == 0) g[50] += tots - wsum; // suffix (raw>=10) -> bin 50
    WAVE_SYNC();
  }
  if (lane < 52) x2[lane] = (lane < 51) ? g[lane] : 0.f;
  WAVE_SYNC();

  // ---- wf projection -> xw row ----
  {
    int MLf, MHf;
    proj_bounds(wfv, MLf, MHf);          // uniform across wave
    int Tf = MHf - MLf;
    if (Tf <= 15) {
      // strided split: lane = q4*16+jj gathers atoms t = q4+4k (no clamp:
      // wv<=~0.3 -> |sup|<=3); combine the 4 quarters with 2 shfl_xor.
      int q4 = lane >> 4, jj = lane & 15;
      float K = (25.0f - (float)(MLf + jj)) - 25.0f * wfv;
      float acc = 0.f;
#pragma unroll
      for (int k = 0; k < 13; ++k) {
        int t = q4 + 4 * k;
        float d = fmaf((float)t, wfv, K);
        acc = fmaf(x2[t], fmaxf(0.f, 1.0f - fabsf(d)), acc);
      }
      acc += __shfl_xor(acc, 16);
      acc += __shfl_xor(acc, 32);
      if (lane <= Tf)                    // Tf<=15 -> lanes 0..15, jj==lane
        xw_ws[task * 51 + MLf + lane] = acc;
    } else {
      float acc = gather_part<0, 13>(x2, wfv, (float)(MLf + lane));
      if (lane <= Tf)
        xw_ws[task * 51 + MLf + lane] = acc;
    }
  }
}

// ====== Kernel 3: TREE convolution — depth 5, 512 threads, R=4 register-
// blocked conv (verified-neutral but correct; kept from Round 6).
__global__ __launch_bounds__(512) void k_final(
    const float* __restrict__ xw_ws, const float* __restrict__ wf_ws,
    const float* __restrict__ v_ws,
    void* __restrict__ out, const int* __restrict__ flag)
{
  __shared__ __align__(16) float bufA[4608];
  __shared__ __align__(16) float bufB[4608];
  __shared__ int meta_s[63];
  __shared__ int meta_l[63];
  __shared__ int meta_ml[32];
  __shared__ int meta_g[6];
  __shared__ int meta_mltot;
  __shared__ float gA[53];

  const int n    = blockIdx.x;
  const int tid  = threadIdx.x;
  const int lane = tid & 63;
  const int bf   = *flag;

  float vv = v_ws[n];

  for (int i = tid; i < 4608; i += 512) { bufA[i] = 0.f; bufB[i] = 0.f; }
  if (tid < 53) gA[tid] = 0.f;

  if (tid < 64) {
    float wfreg = (lane < 32) ? wf_ws[n * 32 + lane] : 0.f;
    int ml, mh;
    proj_bounds(wfreg, ml, mh);
    if (lane < 32) meta_ml[lane] = ml;
    int msum = ml;
#pragma unroll
    for (int d = 1; d < 32; d <<= 1) msum += __shfl_xor(msum, d);
    if (lane == 0) meta_mltot = msum;

    int curlen = mh - ml + 1;
    int base = 0, Ncur = 32;
#pragma unroll
    for (int c = 0; c <= 5; ++c) {
      int lm = (lane < Ncur) ? curlen : 0;
#pragma unroll
      for (int d = 1; d < 32; d <<= 1) {
        int o = __shfl_xor(lm, d);
        lm = (o > lm) ? o : lm;
      }
      int G = (lm + 11) & ~3;
      int sp = ((curlen + 3) & ~3) + G;
      int inc = (lane < Ncur) ? sp : 0;
      int v0 = inc;
#pragma unroll
      for (int d = 1; d < 32; d <<= 1) {
        int u = __shfl_up(inc, d);
        if (lane >= d && lane < 32) inc += u;
      }
      if (lane < Ncur) {
        meta_s[base + lane] = 832 + (inc - v0);
        meta_l[base + lane] = curlen;
      }
      if (lane == 0) meta_g[c] = G;
      if (c < 5) {
        int l0 = __shfl(curlen, 2 * lane);
        int l1 = __shfl(curlen, 2 * lane + 1);
        curlen = l0 + l1 - 1;
        base += Ncur;
        Ncur >>= 1;
      }
    }
  }
  __syncthreads();

  {
    int g = tid >> 4, i3 = tid & 15;     // 16 threads per embed row
    int s2 = meta_s[g], l2 = meta_l[g], ml = meta_ml[g];
    const float* row = xw_ws + (n * 32 + g) * 51 + ml;
    for (int i0 = i3; i0 < l2; i0 += 16) bufA[s2 + i0] = row[i0];
  }
  __syncthreads();

#pragma unroll
  for (int c = 1; c <= 5; ++c) {
    const float* bin = (c & 1) ? bufA : bufB;
    float*       bout = (c & 1) ? bufB : bufA;
    const int Nout = 32 >> c;
    const int lg = 4 + c;                // 512-thread split: gs*Nout == 512
    const int gs = 1 << lg;
    const int k  = tid >> lg;
    const int st = tid & (gs - 1);
    const int bc = 64 - (64 >> c);
    const int bp = 64 - (64 >> (c - 1));
    const int i0 = bp + 2 * k;
    const int sA = meta_s[i0];
    const int sB = meta_s[i0 + 1];
    const int lB = meta_l[i0 + 1];
    const int sO = meta_s[bc + k];
    const int lO = meta_l[bc + k];
    const int W  = (lB + 3) & ~3;
    const int W4 = W >> 2;

    for (int j = st * 4; j < lO; j += gs * 4) {
      const float* Abase = bin + sA + j;
      float a0 = 0.f, a1 = 0.f, a2 = 0.f, a3 = 0.f;
      float q0 = Abase[3],  q1 = Abase[2],  q2 = Abase[1],  q3 = Abase[0],
            q4 = Abase[-1], q5 = Abase[-2], q6 = Abase[-3];
      const float4* kb = (const float4*)(bin + sB);
      for (int g = 0; g < W4; ++g) {
        float4 k4 = kb[g];               // uniform -> broadcast
        a0 = fmaf(k4.x, q3, a0); a1 = fmaf(k4.x, q2, a1);
        a2 = fmaf(k4.x, q1, a2); a3 = fmaf(k4.x, q0, a3);
        a0 = fmaf(k4.y, q4, a0); a1 = fmaf(k4.y, q3, a1);
        a2 = fmaf(k4.y, q2, a2); a3 = fmaf(k4.y, q1, a3);
        a0 = fmaf(k4.z, q5, a0); a1 = fmaf(k4.z, q4, a1);
        a2 = fmaf(k4.z, q3, a2); a3 = fmaf(k4.z, q2, a3);
        a0 = fmaf(k4.w, q6, a0); a1 = fmaf(k4.w, q5, a1);
        a2 = fmaf(k4.w, q4, a2); a3 = fmaf(k4.w, q3, a3);
        q0 = q4; q1 = q5; q2 = q6;
        int b2 = -4 - 4 * g;
        q3 = Abase[b2];     q4 = Abase[b2 - 1];
        q5 = Abase[b2 - 2]; q6 = Abase[b2 - 3];
      }
      bout[sO + j] = a0;
      if (j + 1 < lO) bout[sO + j + 1] = a1;
      if (j + 2 < lO) bout[sO + j + 2] = a2;
      if (j + 3 < lO) bout[sO + j + 3] = a3;
    }

    if (c >= 2 && c <= 4) {
      int G = meta_g[c];
      for (int p = tid; p < G; p += 512) bout[832 - G + p] = 0.f;
      for (int k2 = 0; k2 < Nout; ++k2) {
        int ss = meta_s[bc + k2] + meta_l[bc + k2];
        int ee = (k2 + 1 < Nout) ? meta_s[bc + k2 + 1]
                                 : ss + G + 3;
        for (int p = ss + tid; p < ee; p += 512) bout[p] = 0.f;
      }
    }
    __syncthreads();
  }

  // ---- final projection via LDS atomicAdd across all 512 threads ----
  {
    int s5 = meta_s[62], l5 = meta_l[62], mlt = meta_mltot;
    const float* qf = bufB + s5;
    for (int t = tid; t < l5; t += 512) {
      int tg = mlt + t;
      float sup = (-320.0f + 0.4f * (float)tg) + vv;
      float c  = fminf(fmaxf(sup, -10.0f), 10.0f);
      float b  = (c + 10.0f) / 0.4f;
      float l  = floorf(b);
      float u  = ceilf(b);
      float eq = (u == l) ? 1.0f : 0.0f;
      float p  = qf[t];
      int   li = (int)l;
      atomicAdd(&gA[li],     p * (u - b + eq));
      atomicAdd(&gA[li + 1], p * (b - l));
    }
  }
  __syncthreads();
  if (tid < 51) {
    float o = gA[tid];
    if (bf) ((u16*)out)[n * 51 + tid] = f2bf(o);
    else    ((float*)out)[n * 51 + tid] = o;
  }
}

// =========================== launcher ===========================
extern "C" void kernel_launch(void* const* d_in, const int* in_sizes, int n_in,
                              void* d_out, int out_size, void* d_ws, size_t ws_size,
                              hipStream_t stream)
{
  float* ws    = (float*)d_ws;
  float* w1_ws = ws;                       // 1024*256
  float* b1_ws = w1_ws + 1024 * 256;       // 1024*32
  float* wf_ws = b1_ws + 1024 * 32;        // 1024*32
  float* v_ws  = wf_ws + 1024 * 32;        // 1024
  float* xw_ws = v_ws  + 1024;             // 1024*32*51
  int*   flag  = (int*)(xw_ws + 1024 * 32 * 51);

  k_mlp<<<1024, 320, 0, stream>>>(d_in[1],
      d_in[2], d_in[3], d_in[4], d_in[5], d_in[6], d_in[7],
      d_in[8], d_in[9], d_in[10], d_in[11], d_in[12], d_in[13],
      d_in[14], d_in[15],
      w1_ws, b1_ws, wf_ws, v_ws, flag);

  k_perembed<<<16384, 128, 0, stream>>>(d_in[0], w1_ws, b1_ws, wf_ws, xw_ws, flag);

  k_final<<<1024, 512, 0, stream>>>(xw_ws, wf_ws, v_ws, d_out, flag);
}